// Round 1
// 3385.372 us; speedup vs baseline: 1.1569x; 1.1569x over previous
//
#include <hip/hip_runtime.h>
#include <cstdint>
#include <cstddef>
#include <initializer_list>

typedef short bf16x8 __attribute__((ext_vector_type(8)));
typedef float f32x4 __attribute__((ext_vector_type(4)));

__device__ inline float bf2f(unsigned short h) { return __uint_as_float(((unsigned)h) << 16); }
__device__ inline unsigned short f2bf(float f) {
  unsigned u = __float_as_uint(f);
  u += 0x7fff + ((u >> 16) & 1);
  return (unsigned short)(u >> 16);
}

// ---------------- virtual-A segment for gather-GEMM ----------------
// Each segment is 128 K-rows wide. wk = starting row in W (= col offset in Wt).
// bnsc/bnsh: optional fused BN+ReLU applied to the source on load (per source column).
struct Seg { const void* base; const int* idx; const float* scale; int ld; int wk; int bf16;
             const float* bnsc; const float* bnsh; };
struct GemmArgs { Seg segs[7]; const float* addB; const int* addIdx; float* stats; };

// ---------------- small kernels ----------------
__global__ void k_count(float* dst, const int* __restrict__ idx, int R) {
  int r = blockIdx.x * 256 + threadIdx.x;
  if (r < R) atomicAdd(&dst[idx[r]], 1.0f);
}

__global__ void k_scales(const float* __restrict__ deg, const float* __restrict__ d5,
                         const float* __restrict__ d6, float* deg2, float* dd, int n) {
  int i = blockIdx.x * 256 + threadIdx.x;
  if (i < n) {
    float d = deg[i]; deg2[i] = d * d;
    float a = d5[i], b = d6[i]; dd[i] = a * a + b * b;
  }
}

__global__ void k_wtrans(const float* __restrict__ W, unsigned short* __restrict__ Wt,
                         int K, int CN) {
  int t = blockIdx.x * 256 + threadIdx.x;
  if (t >= K * CN) return;
  int k = t / CN, n = t - k * CN;
  Wt[(size_t)n * K + k] = f2bf(W[t]);
}

__global__ void k_gsum(float* __restrict__ out, int outLd,
                       const float* __restrict__ T, int tLd,
                       const float* __restrict__ scale, const int* __restrict__ idx,
                       int k, int nInst) {
  int t = blockIdx.x * 256 + threadIdx.x;
  int c = t >> 7, ch = t & 127;
  if (c >= nInst) return;
  float acc = 0.f;
  int b0 = c * k;
  for (int j = 0; j < k; ++j) {
    int rid = idx ? idx[b0 + j] : b0 + j;
    float v = T[(size_t)rid * tLd + ch];
    if (scale) v *= scale[rid];
    acc += v;
  }
  out[(size_t)c * outLd + ch] = acc;
}

__global__ void k_scatter(float* __restrict__ dst, const float* __restrict__ src,
                          const int* __restrict__ idx, int R, int C, int div) {
  int r = blockIdx.x;
  if (r >= R) return;
  int n = idx[r];
  const float* s = src + (size_t)(r / div) * C;
  float* d = dst + (size_t)n * C;
  for (int c = threadIdx.x; c < C; c += blockDim.x)
    atomicAdd(&d[c], s[c]);
}

// stats[c]=sum, stats[C+c]=sumsq  ->  coef[c]=scale, coef[C+c]=shift
__global__ void k_bnfin(float* __restrict__ coef, const float* __restrict__ stats,
                        const float* __restrict__ g, const float* __restrict__ b,
                        int M, int C) {
  int c = threadIdx.x;
  if (c >= C) return;
  float inv = 1.f / (float)M;
  float m = stats[c] * inv;
  float v = stats[C + c] * inv - m * m;
  float s = g[c] * rsqrtf(v + 1e-5f);
  coef[c] = s;
  coef[C + c] = b[c] - m * s;
}

// ---------------- MFMA gather-GEMM: C[M,CN] = A_virtual[M, 128*nseg] @ W ----------------
// 128x128 tile, BK=32, 256 thr = 4 waves (2x2), mfma_f32_16x16x32_bf16, 4x4 acc/wave.
// Pipelined: register prefetch of next K-tile + LDS double-buffer (1 barrier/iter).
// Optional fused BN+ReLU on A-load (per seg) and fused per-column sum/sumsq epilogue.
template <int OUT_BF16>
__launch_bounds__(256)
__global__ void k_gemm(GemmArgs ga, const unsigned short* __restrict__ Wt, int Ktot,
                       int K, int CN, void* __restrict__ Cp, int M) {
  __shared__ char AsB[2 * 128 * 64];
  __shared__ char BsB[2 * 128 * 64];
  int tid = threadIdx.x;
  int row0 = blockIdx.x * 128, col0 = blockIdx.y * 128;
  int l = tid & 63, w = tid >> 6;
  int wm = w >> 1, wn = w & 1;
  int lr = l & 15, g = l >> 4;
  int chunkOff = (g ^ ((lr >> 1) & 3)) << 4;
  int sm = tid >> 2;          // staging row 0..63 (+64 for h=1)
  int sc4 = tid & 3;          // staging 16B chunk
  f32x4 acc[4][4] = {};

  // prefetch registers
  uint4 pa0[2], pa1[2], pb[2];
  float psc[2];
  float4 c0, c1, c2, c3;

  auto issue = [&](int k0n) {
    Seg sg = ga.segs[k0n >> 7];
    int kin = k0n & 127;
#pragma unroll
    for (int h = 0; h < 2; ++h) {
      int m = sm + 64 * h;
      int grow = row0 + m;
      uint4 z4 = make_uint4(0, 0, 0, 0);
      pa0[h] = z4; pa1[h] = z4; psc[h] = 1.f;
      if (grow < M) {
        int rid = sg.idx ? sg.idx[grow] : grow;
        if (sg.bf16) {
          pa0[h] = *(const uint4*)((const unsigned short*)sg.base + (size_t)rid * sg.ld + kin + sc4 * 8);
        } else {
          const float* fp = (const float*)sg.base + (size_t)rid * sg.ld + kin + sc4 * 8;
          pa0[h] = *(const uint4*)fp;
          pa1[h] = *(const uint4*)(fp + 4);
          if (sg.scale) psc[h] = sg.scale[rid];
        }
      }
      pb[h] = *(const uint4*)(Wt + (size_t)(col0 + m) * Ktot + sg.wk + kin + sc4 * 8);
    }
    if (sg.bnsc) {
      const float* sp = sg.bnsc + kin + sc4 * 8;
      const float* hp = sg.bnsh + kin + sc4 * 8;
      c0 = *(const float4*)sp; c1 = *(const float4*)(sp + 4);
      c2 = *(const float4*)hp; c3 = *(const float4*)(hp + 4);
    }
  };

  issue(0);
  int buf = 0;
  for (int k0 = 0; k0 < K; k0 += 32) {
    // commit prefetched regs -> LDS[buf]
    {
      Seg sg = ga.segs[k0 >> 7];
      char* sA = AsB + buf * 8192;
      char* sB = BsB + buf * 8192;
#pragma unroll
      for (int h = 0; h < 2; ++h) {
        int m = sm + 64 * h;
        uint4 pk;
        if (sg.bf16) {
          pk = pa0[h];
          if (sg.bnsc) {
            unsigned short* u = (unsigned short*)&pk;
            float cs0[8] = {c0.x, c0.y, c0.z, c0.w, c1.x, c1.y, c1.z, c1.w};
            float sh0[8] = {c2.x, c2.y, c2.z, c2.w, c3.x, c3.y, c3.z, c3.w};
#pragma unroll
            for (int e = 0; e < 8; ++e) {
              float f = fmaxf(0.f, bf2f(u[e]) * cs0[e] + sh0[e]);
              u[e] = f2bf(f);
            }
          }
        } else {
          float4 v0 = *(const float4*)&pa0[h];
          float4 v1 = *(const float4*)&pa1[h];
          float s = psc[h];
          v0.x *= s; v0.y *= s; v0.z *= s; v0.w *= s;
          v1.x *= s; v1.y *= s; v1.z *= s; v1.w *= s;
          if (sg.bnsc) {
            v0.x = fmaxf(0.f, v0.x * c0.x + c2.x);
            v0.y = fmaxf(0.f, v0.y * c0.y + c2.y);
            v0.z = fmaxf(0.f, v0.z * c0.z + c2.z);
            v0.w = fmaxf(0.f, v0.w * c0.w + c2.w);
            v1.x = fmaxf(0.f, v1.x * c1.x + c3.x);
            v1.y = fmaxf(0.f, v1.y * c1.y + c3.y);
            v1.z = fmaxf(0.f, v1.z * c1.z + c3.z);
            v1.w = fmaxf(0.f, v1.w * c1.w + c3.w);
          }
          pk.x = f2bf(v0.x) | ((unsigned)f2bf(v0.y) << 16);
          pk.y = f2bf(v0.z) | ((unsigned)f2bf(v0.w) << 16);
          pk.z = f2bf(v1.x) | ((unsigned)f2bf(v1.y) << 16);
          pk.w = f2bf(v1.z) | ((unsigned)f2bf(v1.w) << 16);
        }
        *(uint4*)(sA + m * 64 + ((sc4 ^ ((m >> 1) & 3)) << 4)) = pk;
        *(uint4*)(sB + m * 64 + ((sc4 ^ ((m >> 1) & 3)) << 4)) = pb[h];
      }
    }
    __syncthreads();
    // issue next tile's global loads; they fly during ds_read+MFMA below
    if (k0 + 32 < K) issue(k0 + 32);
    const char* lA = AsB + buf * 8192;
    const char* lB = BsB + buf * 8192;
    bf16x8 a[4], b4[4];
#pragma unroll
    for (int i = 0; i < 4; ++i) {
      int m = wm * 64 + i * 16 + lr;
      a[i] = *(const bf16x8*)(lA + m * 64 + chunkOff);
    }
#pragma unroll
    for (int j = 0; j < 4; ++j) {
      int n = wn * 64 + j * 16 + lr;
      b4[j] = *(const bf16x8*)(lB + n * 64 + chunkOff);
    }
#pragma unroll
    for (int i = 0; i < 4; ++i)
#pragma unroll
      for (int j = 0; j < 4; ++j)
        acc[i][j] = __builtin_amdgcn_mfma_f32_16x16x32_bf16(a[i], b4[j], acc[i][j], 0, 0, 0);
    buf ^= 1;
    // no trailing barrier: next commit writes the other LDS buffer; passing the
    // next barrier implies all waves finished this buffer's MFMA reads.
  }

  // epilogue: C/D layout col=lane&15, row=(lane>>4)*4+reg (m89-verified)
  float csum[4] = {0.f, 0.f, 0.f, 0.f}, cqum[4] = {0.f, 0.f, 0.f, 0.f};
#pragma unroll
  for (int i = 0; i < 4; ++i) {
#pragma unroll
    for (int r = 0; r < 4; ++r) {
      int grow = row0 + wm * 64 + i * 16 + g * 4 + r;
      if (grow >= M) continue;
      const float* zr = nullptr;
      if (ga.addB) {
        int rid = ga.addIdx ? ga.addIdx[grow] : grow;
        zr = ga.addB + (size_t)rid * 256;
      }
#pragma unroll
      for (int j = 0; j < 4; ++j) {
        int col = col0 + wn * 64 + j * 16 + lr;
        float o = acc[i][j][r];
        if (zr) o += zr[col];
        csum[j] += o; cqum[j] += o * o;
        if (OUT_BF16) ((unsigned short*)Cp)[(size_t)grow * CN + col] = f2bf(o);
        else          ((float*)Cp)[(size_t)grow * CN + col] = o;
      }
    }
  }
  // fused BN stats: per-column sum/sumsq. Lanes sharing a column differ only in g.
  if (ga.stats) {
#pragma unroll
    for (int j = 0; j < 4; ++j) {
      float s = csum[j], q = cqum[j];
      s += __shfl_xor(s, 16); q += __shfl_xor(q, 16);
      s += __shfl_xor(s, 32); q += __shfl_xor(q, 32);
      if (g == 0) {
        int col = col0 + wn * 64 + j * 16 + lr;
        atomicAdd(&ga.stats[col], s);
        atomicAdd(&ga.stats[CN + col], q);
      }
    }
  }
}

// ---------------- batchnorm apply (final outputs only; reads fused stats) --------------
template <int SB, int DB>
__global__ void k_bnapply(void* __restrict__ dst, const void* __restrict__ yv,
                          const float* __restrict__ g, const float* __restrict__ b,
                          const float* __restrict__ stats, int M, int C) {
  int t = blockIdx.x * 256 + threadIdx.x;
  if (t >= M * C) return;
  int c = t & (C - 1);
  float inv = 1.0f / (float)M;
  float m = stats[c] * inv;
  float v = stats[C + c] * inv - m * m;
  float sc = g[c] * rsqrtf(v + 1e-5f);
  float sh = b[c] - m * sc;
  float x = SB ? bf2f(((const unsigned short*)yv)[t]) : ((const float*)yv)[t];
  x = x * sc + sh;
  x = x > 0.f ? x : 0.f;
  if (DB) ((unsigned short*)dst)[t] = f2bf(x);
  else    ((float*)dst)[t] = x;
}

// ---------------- host ----------------
extern "C" void kernel_launch(void* const* d_in, const int* in_sizes, int n_in,
                              void* d_out, int out_size, void* d_ws, size_t ws_size,
                              hipStream_t stream) {
  constexpr int N = 50000, E = 100000, C5 = 8000, C6 = 12000;
  constexpr int RE = 2 * E, R5 = 5 * C5, R6 = 6 * C6, NC = R5 + R6, CC = C5 + C6;

  const float* node_rep  = (const float*)d_in[0];
  const float* edge_rep  = (const float*)d_in[1];
  const float* cycle_rep = (const float*)d_in[2];
  const int* en  = (const int*)d_in[3];
  const int* cn5 = (const int*)d_in[4];
  const int* cn6 = (const int*)d_in[5];
  const float* nm_w1 = (const float*)d_in[6],  *nm_g1 = (const float*)d_in[7],  *nm_b1 = (const float*)d_in[8];
  const float* nm_w2 = (const float*)d_in[9],  *nm_g2 = (const float*)d_in[10], *nm_b2 = (const float*)d_in[11];
  const float* em_w1 = (const float*)d_in[12], *em_g1 = (const float*)d_in[13], *em_b1 = (const float*)d_in[14];
  const float* em_w2 = (const float*)d_in[15], *em_g2 = (const float*)d_in[16], *em_b2 = (const float*)d_in[17];
  const float* ce_w1 = (const float*)d_in[18], *ce_g1 = (const float*)d_in[19], *ce_b1 = (const float*)d_in[20];
  const float* ce_w2 = (const float*)d_in[21], *ce_g2 = (const float*)d_in[22], *ce_b2 = (const float*)d_in[23];
  const float* cm_w1 = (const float*)d_in[24], *cm_g1 = (const float*)d_in[25], *cm_b1 = (const float*)d_in[26];
  const float* cm_w2 = (const float*)d_in[27], *cm_g2 = (const float*)d_in[28], *cm_b2 = (const float*)d_in[29];
  const float* fm_w  = (const float*)d_in[30], *fm_g  = (const float*)d_in[31], *fm_b  = (const float*)d_in[32];
  float* outD = (float*)d_out;
  float* outN = outD;
  float* outE = outD + (size_t)N * 128;
  float* outC = outD + (size_t)(N + RE) * 128;

  // ---- byte-granular arena ----
  char* wsb = (char*)d_ws;
  size_t off = 0;
  auto A = [&](size_t bytes) { void* p = wsb + off; off += (bytes + 255) & ~(size_t)255; return p; };
  float* deg = (float*)A(N * 4);
  float* d5  = (float*)A(N * 4);
  float* d6  = (float*)A(N * 4);
  float* Ae  = (float*)A((size_t)N * 128 * 4);
  float* Be  = (float*)A((size_t)N * 128 * 4);
  float* Bn  = (float*)A((size_t)N * 128 * 4);
  float* pb2 = (float*)A((size_t)N * 256 * 4);
  float* pb5 = (float*)A((size_t)N * 256 * 4);
  float* pb6 = (float*)A((size_t)N * 256 * 4);
  float* Ac  = (float*)A((size_t)N * 128 * 4);
  size_t zeroBytes = off;                       // everything above is scatter-target
  float* deg2 = (float*)A(N * 4);
  float* dd   = (float*)A(N * 4);
  float* Z    = (float*)A((size_t)N * 256 * 4);
  float* stats = (float*)A(512 * 4);
  float* coefCe1 = (float*)A(512 * 4);
  float* coefCe2 = (float*)A(512 * 4);
  float* coefEm1 = (float*)A(512 * 4);
  float* coefEm2 = (float*)A(512 * 4);
  float* coefNm1 = (float*)A(512 * 4);
  float* coefCm1 = (float*)A(512 * 4);
  // bf16 transposed weights
  unsigned short* WtNm1 = (unsigned short*)A((size_t)896 * 256 * 2);
  unsigned short* WtEm1 = (unsigned short*)A((size_t)896 * 256 * 2);
  unsigned short* WtCe1 = (unsigned short*)A((size_t)1408 * 256 * 2);
  unsigned short* WtCm1 = (unsigned short*)A((size_t)640 * 256 * 2);
  unsigned short* WtNm2 = (unsigned short*)A((size_t)256 * 128 * 2);
  unsigned short* WtEm2 = (unsigned short*)A((size_t)256 * 128 * 2);
  unsigned short* WtCe2 = (unsigned short*)A((size_t)256 * 128 * 2);
  unsigned short* WtCm2 = (unsigned short*)A((size_t)256 * 128 * 2);
  unsigned short* WtFm  = (unsigned short*)A((size_t)256 * 128 * 2);
  char*  Yb   = (char*)A((size_t)RE * 256 * 2); // bf16 y arena; aliased as fp32 staging
  unsigned short* O2 = (unsigned short*)A((size_t)RE * 128 * 2);
  if (off > ws_size) return;                    // ~465 MB required

  // staging views inside Yb (liveness-disjoint with bf16 y use)
  float* s2 = (float*)Yb;               // [E,128]
  float* sN = s2 + (size_t)E * 128;     // [E,128]
  float* s3 = (float*)Yb;               // [E,256]
  float* s5 = (float*)Yb;               // [C5,256]
  float* s6 = s5 + (size_t)C5 * 256;    // [C6,256]
  float* scb = (float*)Yb;              // [CC,640]
  float* Ysc = scb + (size_t)CC * 640;  // [CC,256]

  auto gsum = [&](float* o, int oLd, const float* T, int tLd,
                  const float* scl, const int* idx, int k, int nInst) {
    int tot = nInst * 128;
    k_gsum<<<(tot + 255) / 256, 256, 0, stream>>>(o, oLd, T, tLd, scl, idx, k, nInst);
  };
  auto scat = [&](float* dst, const float* src, const int* idx, int R, int C, int dv) {
    k_scatter<<<R, 128, 0, stream>>>(dst, src, idx, R, C, dv);
  };
  auto wtr = [&](const float* W, unsigned short* Wt, int K, int CN) {
    k_wtrans<<<(K * CN + 255) / 256, 256, 0, stream>>>(W, Wt, K, CN);
  };
  auto gemm = [&](std::initializer_list<Seg> segs, const unsigned short* Wt, int Ktot,
                  int CN, void* Co, int M, bool outBf, const float* addB, const int* addIdx,
                  float* st) {
    GemmArgs ga{}; int i = 0;
    for (const Seg& s : segs) ga.segs[i++] = s;
    ga.addB = addB; ga.addIdx = addIdx; ga.stats = st;
    int K = i * 128;
    dim3 g((M + 127) / 128, CN / 128);
    if (outBf) k_gemm<1><<<g, 256, 0, stream>>>(ga, Wt, Ktot, K, CN, Co, M);
    else       k_gemm<0><<<g, 256, 0, stream>>>(ga, Wt, Ktot, K, CN, Co, M);
  };
  auto zstat = [&](int C) { hipMemsetAsync(stats, 0, 2 * C * sizeof(float), stream); };
  auto fin = [&](float* coef, const float* g, const float* b, int M, int C) {
    k_bnfin<<<1, 256, 0, stream>>>(coef, stats, g, b, M, C);
  };
  auto apply = [&](void* dst, const void* y, const float* g, const float* b,
                   int M, int C, int sb, int db) {
    int tot = M * C, gb = (tot + 255) / 256;
    if (sb && db)       k_bnapply<1, 1><<<gb, 256, 0, stream>>>(dst, y, g, b, stats, M, C);
    else if (sb && !db) k_bnapply<1, 0><<<gb, 256, 0, stream>>>(dst, y, g, b, stats, M, C);
    else if (!sb && db) k_bnapply<0, 1><<<gb, 256, 0, stream>>>(dst, y, g, b, stats, M, C);
    else                k_bnapply<0, 0><<<gb, 256, 0, stream>>>(dst, y, g, b, stats, M, C);
  };

  // ---- phase 0: degrees + weight transposes ----
  hipMemsetAsync(d_ws, 0, zeroBytes, stream);
  k_count<<<(RE + 255) / 256, 256, 0, stream>>>(deg, en, RE);
  k_count<<<(R5 + 255) / 256, 256, 0, stream>>>(d5, cn5, R5);
  k_count<<<(R6 + 255) / 256, 256, 0, stream>>>(d6, cn6, R6);
  k_scales<<<(N + 255) / 256, 256, 0, stream>>>(deg, d5, d6, deg2, dd, N);
  wtr(nm_w1, WtNm1, 896, 256);  wtr(em_w1, WtEm1, 896, 256);
  wtr(ce_w1, WtCe1, 1408, 256); wtr(cm_w1, WtCm1, 640, 256);
  wtr(nm_w2, WtNm2, 256, 128);  wtr(em_w2, WtEm2, 256, 128);
  wtr(ce_w2, WtCe2, 256, 128);  wtr(cm_w2, WtCm2, 256, 128);
  wtr(fm_w,  WtFm,  256, 128);

  // ---- phase 1: edge-node tables ----
  gsum(s2, 128, edge_rep, 128, nullptr, nullptr, 2, E);
  gsum(sN, 128, node_rep, 128, nullptr, en, 2, E);
  scat(Ae, edge_rep, en, RE, 128, 1);
  scat(Be, s2, en, RE, 128, 2);
  scat(Bn, sN, en, RE, 128, 2);
  gsum(s3, 256, Ae, 128, nullptr, en, 2, E);
  gsum(s3 + 128, 256, Be, 128, nullptr, en, 2, E);
  scat(pb2, s3, en, RE, 256, 2);

  // ---- phase 2: cycle tables ----
  gsum(s5, 256, Ae, 128, nullptr, cn5, 5, C5);
  gsum(s5 + 128, 256, Be, 128, nullptr, cn5, 5, C5);
  gsum(s6, 256, Ae, 128, nullptr, cn6, 6, C6);
  gsum(s6 + 128, 256, Be, 128, nullptr, cn6, 6, C6);
  scat(pb5, s5, cn5, R5, 256, 5);
  scat(pb6, s6, cn6, R6, 256, 6);
  scat(Ac, cycle_rep, cn5, R5, 128, 1);
  scat(Ac, cycle_rep + (size_t)R5 * 128, cn6, R6, 128, 1);

  // ---- ce stage ----
  gsum(scb + 0,   640, Ae, 128, d5, cn5, 5, C5);
  gsum(scb + 128, 640, Be, 128, d5, cn5, 5, C5);
  gsum(scb + 256, 640, pb5, 256, nullptr, cn5, 5, C5);
  gsum(scb + 384, 640, pb5 + 128, 256, nullptr, cn5, 5, C5);
  gsum(scb + 512, 640, cycle_rep, 128, nullptr, nullptr, 5, C5);
  float* sc6 = scb + (size_t)C5 * 640;
  gsum(sc6 + 0,   640, Ae, 128, d6, cn6, 6, C6);
  gsum(sc6 + 128, 640, Be, 128, d6, cn6, 6, C6);
  gsum(sc6 + 256, 640, pb6, 256, nullptr, cn6, 6, C6);
  gsum(sc6 + 384, 640, pb6 + 128, 256, nullptr, cn6, 6, C6);
  gsum(sc6 + 512, 640, cycle_rep + (size_t)R5 * 128, 128, nullptr, nullptr, 6, C6);
  gemm({{scb, nullptr, nullptr, 640, 768, 0}, {scb + 128, nullptr, nullptr, 640, 896, 0},
        {scb + 256, nullptr, nullptr, 640, 1024, 0}, {scb + 384, nullptr, nullptr, 640, 1152, 0},
        {scb + 512, nullptr, nullptr, 640, 1280, 0}},
       WtCe1, 1408, 256, Ysc, CC, false, nullptr, nullptr, nullptr);
  gemm({{Ae, nullptr, dd, 128, 128, 0}, {Be, nullptr, dd, 128, 256, 0},
        {pb5, nullptr, d5, 256, 384, 0}, {pb5 + 128, nullptr, d5, 256, 512, 0},
        {pb6, nullptr, d6, 256, 384, 0}, {pb6 + 128, nullptr, d6, 256, 512, 0},
        {Ac, nullptr, nullptr, 128, 640, 0}},
       WtCe1, 1408, 256, Z, N, false, nullptr, nullptr, nullptr);
  scat(Z, Ysc, cn5, R5, 256, 5);
  scat(Z, Ysc + (size_t)C5 * 256, cn6, R6, 256, 6);
  zstat(256);
  gemm({{edge_rep, nullptr, nullptr, 128, 0, 0}}, WtCe1, 1408, 256, Yb, RE, true, Z, en, stats);
  fin(coefCe1, ce_g1, ce_b1, RE, 256);
  zstat(128);
  gemm({{Yb, nullptr, nullptr, 256, 0, 1, coefCe1, coefCe1 + 256},
        {Yb + 256, nullptr, nullptr, 256, 128, 1, coefCe1 + 128, coefCe1 + 384}},
       WtCe2, 256, 128, O2, RE, true, nullptr, nullptr, stats);
  fin(coefCe2, ce_g2, ce_b2, RE, 128);

  // ---- em stage ----
  gemm({{Ae, nullptr, deg, 128, 128, 0}, {Be, nullptr, deg, 128, 256, 0},
        {pb2, nullptr, nullptr, 256, 384, 0}, {pb2 + 128, nullptr, nullptr, 256, 512, 0},
        {node_rep, nullptr, deg, 128, 640, 0}, {Bn, nullptr, nullptr, 128, 768, 0}},
       WtEm1, 896, 256, Z, N, false, nullptr, nullptr, nullptr);
  zstat(256);
  gemm({{edge_rep, nullptr, nullptr, 128, 0, 0}}, WtEm1, 896, 256, Yb, RE, true, Z, en, stats);
  fin(coefEm1, em_g1, em_b1, RE, 256);
  zstat(128);
  gemm({{Yb, nullptr, nullptr, 256, 0, 1, coefEm1, coefEm1 + 256},
        {Yb + 256, nullptr, nullptr, 256, 128, 1, coefEm1 + 128, coefEm1 + 384}},
       WtEm2, 256, 128, outE, RE, false, nullptr, nullptr, stats); // raw y2 -> outE (scratch)
  fin(coefEm2, em_g2, em_b2, RE, 128);

  // ---- nm stage ----
  zstat(256);
  gemm({{node_rep, nullptr, nullptr, 128, 0, 0}, {Ae, nullptr, deg2, 128, 128, 0},
        {Be, nullptr, deg2, 128, 256, 0}, {pb2, nullptr, deg, 256, 384, 0},
        {pb2 + 128, nullptr, deg, 256, 512, 0}, {node_rep, nullptr, deg2, 128, 640, 0},
        {Bn, nullptr, deg, 128, 768, 0}},
       WtNm1, 896, 256, Yb, N, true, nullptr, nullptr, stats);
  fin(coefNm1, nm_g1, nm_b1, N, 256);
  zstat(128);
  gemm({{Yb, nullptr, nullptr, 256, 0, 1, coefNm1, coefNm1 + 256},
        {Yb + 256, nullptr, nullptr, 256, 128, 1, coefNm1 + 128, coefNm1 + 384}},
       WtNm2, 256, 128, outN, N, false, nullptr, nullptr, stats);
  apply(outN, outN, nm_g2, nm_b2, N, 128, 0, 0);

  // ---- cm stage ----
  gemm({{Ae, nullptr, d5, 128, 0, 0}, {Be, nullptr, d5, 128, 128, 0},
        {pb5, nullptr, nullptr, 256, 256, 0}, {pb5 + 128, nullptr, nullptr, 256, 384, 0}},
       WtCm1, 640, 256, Z, N, false, nullptr, nullptr, nullptr);
  zstat(256);
  gemm({{cycle_rep, nullptr, nullptr, 128, 512, 0}}, WtCm1, 640, 256, Yb, R5, true, Z, cn5, stats);
  gemm({{Ae, nullptr, d6, 128, 0, 0}, {Be, nullptr, d6, 128, 128, 0},
        {pb6, nullptr, nullptr, 256, 256, 0}, {pb6 + 128, nullptr, nullptr, 256, 384, 0}},
       WtCm1, 640, 256, Z, N, false, nullptr, nullptr, nullptr);
  gemm({{cycle_rep + (size_t)R5 * 128, nullptr, nullptr, 128, 512, 0}}, WtCm1, 640, 256,
       Yb + (size_t)R5 * 256 * 2, R6, true, Z, cn6, stats);
  fin(coefCm1, cm_g1, cm_b1, NC, 256);
  zstat(128);
  gemm({{Yb, nullptr, nullptr, 256, 0, 1, coefCm1, coefCm1 + 256},
        {Yb + 256, nullptr, nullptr, 256, 128, 1, coefCm1 + 128, coefCm1 + 384}},
       WtCm2, 256, 128, outC, NC, false, nullptr, nullptr, stats);
  apply(outC, outC, cm_g2, cm_b2, NC, 128, 0, 0);

  // ---- fm stage ----
  zstat(128);
  gemm({{outE, nullptr, nullptr, 128, 0, 0, coefEm2, coefEm2 + 128},
        {O2, nullptr, nullptr, 128, 128, 1, coefCe2, coefCe2 + 128}},
       WtFm, 256, 128, Yb, RE, true, nullptr, nullptr, stats);
  apply(outE, Yb, fm_g, fm_b, RE, 128, 1, 0);
}

// Round 2
// 2870.752 us; speedup vs baseline: 1.3643x; 1.1793x over previous
//
#include <hip/hip_runtime.h>
#include <cstdint>
#include <cstddef>
#include <initializer_list>

typedef short bf16x8 __attribute__((ext_vector_type(8)));
typedef float f32x4 __attribute__((ext_vector_type(4)));

__device__ inline float bf2f(unsigned short h) { return __uint_as_float(((unsigned)h) << 16); }
__device__ inline unsigned short f2bf(float f) {
  unsigned u = __float_as_uint(f);
  u += 0x7fff + ((u >> 16) & 1);
  return (unsigned short)(u >> 16);
}

// ---------------- virtual-A segment for gather-GEMM ----------------
// Each segment is 128 K-rows wide. wk = starting row in W (= col offset in Wt).
// bnsc/bnsh: optional fused BN+ReLU applied to the source on load (per source column).
struct Seg { const void* base; const int* idx; const float* scale; int ld; int wk; int bf16;
             const float* bnsc; const float* bnsh; };
struct GemmArgs { Seg segs[7]; const float* addB; const int* addIdx; float* stats; int addBf16; };

// ---------------- small kernels ----------------
__global__ void k_count(float* dst, const int* __restrict__ idx, int R) {
  int r = blockIdx.x * 256 + threadIdx.x;
  if (r < R) atomicAdd(&dst[idx[r]], 1.0f);
}

__global__ void k_scales(const float* __restrict__ deg, const float* __restrict__ d5,
                         const float* __restrict__ d6, float* deg2, float* dd, int n) {
  int i = blockIdx.x * 256 + threadIdx.x;
  if (i < n) {
    float d = deg[i]; deg2[i] = d * d;
    float a = d5[i], b = d6[i]; dd[i] = a * a + b * b;
  }
}

__global__ void k_wtrans(const float* __restrict__ W, unsigned short* __restrict__ Wt,
                         int K, int CN) {
  int t = blockIdx.x * 256 + threadIdx.x;
  if (t >= K * CN) return;
  int k = t / CN, n = t - k * CN;
  Wt[(size_t)n * K + k] = f2bf(W[t]);
}

__global__ void k_cvt(unsigned short* __restrict__ dst, const float* __restrict__ src, int n8) {
  int i = blockIdx.x * 256 + threadIdx.x;
  if (i >= n8) return;
  const float4* s = (const float4*)(src + (size_t)i * 8);
  float4 a = s[0], b = s[1];
  union { unsigned short u[8]; uint4 v; } o;
  o.u[0] = f2bf(a.x); o.u[1] = f2bf(a.y); o.u[2] = f2bf(a.z); o.u[3] = f2bf(a.w);
  o.u[4] = f2bf(b.x); o.u[5] = f2bf(b.y); o.u[6] = f2bf(b.z); o.u[7] = f2bf(b.w);
  *(uint4*)(dst + (size_t)i * 8) = o.v;
}

__global__ void k_gsum(float* __restrict__ out, int outLd,
                       const float* __restrict__ T, int tLd,
                       const float* __restrict__ scale, const int* __restrict__ idx,
                       int k, int nInst) {
  int t = blockIdx.x * 256 + threadIdx.x;
  int c = t >> 7, ch = t & 127;
  if (c >= nInst) return;
  float acc = 0.f;
  int b0 = c * k;
  for (int j = 0; j < k; ++j) {
    int rid = idx ? idx[b0 + j] : b0 + j;
    float v = T[(size_t)rid * tLd + ch];
    if (scale) v *= scale[rid];
    acc += v;
  }
  out[(size_t)c * outLd + ch] = acc;
}

// fused gsum+scatter: per instance c, sum = sum_j T[rid(c,j)] (T1|T2 for 256-wide),
// then dst[sidx[c*k+j]] += sum for all j. Saves the intermediate table round-trip.
__global__ void k_gsc(float* __restrict__ dst, const float* __restrict__ T1,
                      const float* __restrict__ T2, const int* __restrict__ gidx,
                      const int* __restrict__ sidx, int k, int nInst, int cshift) {
  int t = blockIdx.x * 256 + threadIdx.x;
  int c = t >> cshift;
  int C = 1 << cshift;
  int ch = t & (C - 1);
  if (c >= nInst) return;
  const float* T = (ch < 128) ? T1 : T2;
  int ch7 = ch & 127;
  float acc = 0.f;
  int b0 = c * k;
  for (int j = 0; j < k; ++j) {
    int rid = gidx ? gidx[b0 + j] : b0 + j;
    acc += T[(size_t)rid * 128 + ch7];
  }
  for (int j = 0; j < k; ++j)
    atomicAdd(&dst[(size_t)sidx[b0 + j] * C + ch], acc);
}

__global__ void k_scatter(float* __restrict__ dst, const float* __restrict__ src,
                          const int* __restrict__ idx, int R, int C, int div) {
  int r = blockIdx.x;
  if (r >= R) return;
  int n = idx[r];
  const float* s = src + (size_t)(r / div) * C;
  float* d = dst + (size_t)n * C;
  for (int c = threadIdx.x; c < C; c += blockDim.x)
    atomicAdd(&d[c], s[c]);
}

// sharded stats[16][512]: sums at [s*512+c], sumsq at [s*512+256+c] -> coef {scale, shift}
__global__ void k_bnfin(float* __restrict__ coef, const float* __restrict__ stats,
                        const float* __restrict__ g, const float* __restrict__ b,
                        int M, int C) {
  int c = threadIdx.x;
  if (c >= C) return;
  float s = 0.f, q = 0.f;
  for (int sh = 0; sh < 16; ++sh) { s += stats[sh * 512 + c]; q += stats[sh * 512 + 256 + c]; }
  float inv = 1.f / (float)M;
  float m = s * inv;
  float v = q * inv - m * m;
  float sc = g[c] * rsqrtf(v + 1e-5f);
  coef[c] = sc;
  coef[C + c] = b[c] - m * sc;
}

// ---------------- MFMA gather-GEMM: C[M,CN] = A_virtual[M, 128*nseg] @ W ----------------
// 128x128 tile, BK=32, 256 thr = 4 waves (2x2), mfma_f32_16x16x32_bf16, 4x4 acc/wave.
// Pipelined: register prefetch of next K-tile + LDS double-buffer (1 barrier/iter).
// Optional fused BN+ReLU on A-load (per seg), fused addB gather (f32 or bf16),
// and fused per-column sum/sumsq epilogue into 16-way sharded stats.
template <int OUT_BF16>
__launch_bounds__(256)
__global__ void k_gemm(GemmArgs ga, const unsigned short* __restrict__ Wt, int Ktot,
                       int K, int CN, void* __restrict__ Cp, int M) {
  __shared__ char AsB[2 * 128 * 64];
  __shared__ char BsB[2 * 128 * 64];
  int tid = threadIdx.x;
  int row0 = blockIdx.x * 128, col0 = blockIdx.y * 128;
  int l = tid & 63, w = tid >> 6;
  int wm = w >> 1, wn = w & 1;
  int lr = l & 15, g = l >> 4;
  int chunkOff = (g ^ ((lr >> 1) & 3)) << 4;
  int sm = tid >> 2;          // staging row 0..63 (+64 for h=1)
  int sc4 = tid & 3;          // staging 16B chunk
  f32x4 acc[4][4] = {};

  // prefetch registers
  uint4 pa0[2], pa1[2], pb[2];
  float psc[2];
  float4 c0, c1, c2, c3;

  auto issue = [&](int k0n) {
    Seg sg = ga.segs[k0n >> 7];
    int kin = k0n & 127;
#pragma unroll
    for (int h = 0; h < 2; ++h) {
      int m = sm + 64 * h;
      int grow = row0 + m;
      uint4 z4 = make_uint4(0, 0, 0, 0);
      pa0[h] = z4; pa1[h] = z4; psc[h] = 1.f;
      if (grow < M) {
        int rid = sg.idx ? sg.idx[grow] : grow;
        if (sg.bf16) {
          pa0[h] = *(const uint4*)((const unsigned short*)sg.base + (size_t)rid * sg.ld + kin + sc4 * 8);
        } else {
          const float* fp = (const float*)sg.base + (size_t)rid * sg.ld + kin + sc4 * 8;
          pa0[h] = *(const uint4*)fp;
          pa1[h] = *(const uint4*)(fp + 4);
          if (sg.scale) psc[h] = sg.scale[rid];
        }
      }
      pb[h] = *(const uint4*)(Wt + (size_t)(col0 + m) * Ktot + sg.wk + kin + sc4 * 8);
    }
    if (sg.bnsc) {
      const float* sp = sg.bnsc + kin + sc4 * 8;
      const float* hp = sg.bnsh + kin + sc4 * 8;
      c0 = *(const float4*)sp; c1 = *(const float4*)(sp + 4);
      c2 = *(const float4*)hp; c3 = *(const float4*)(hp + 4);
    }
  };

  issue(0);
  int buf = 0;
  for (int k0 = 0; k0 < K; k0 += 32) {
    // commit prefetched regs -> LDS[buf]
    {
      Seg sg = ga.segs[k0 >> 7];
      char* sA = AsB + buf * 8192;
      char* sB = BsB + buf * 8192;
#pragma unroll
      for (int h = 0; h < 2; ++h) {
        int m = sm + 64 * h;
        uint4 pk;
        if (sg.bf16) {
          pk = pa0[h];
          if (sg.bnsc) {
            unsigned short* u = (unsigned short*)&pk;
            float cs0[8] = {c0.x, c0.y, c0.z, c0.w, c1.x, c1.y, c1.z, c1.w};
            float sh0[8] = {c2.x, c2.y, c2.z, c2.w, c3.x, c3.y, c3.z, c3.w};
#pragma unroll
            for (int e = 0; e < 8; ++e) {
              float f = fmaxf(0.f, bf2f(u[e]) * cs0[e] + sh0[e]);
              u[e] = f2bf(f);
            }
          }
        } else {
          float4 v0 = *(const float4*)&pa0[h];
          float4 v1 = *(const float4*)&pa1[h];
          float s = psc[h];
          v0.x *= s; v0.y *= s; v0.z *= s; v0.w *= s;
          v1.x *= s; v1.y *= s; v1.z *= s; v1.w *= s;
          if (sg.bnsc) {
            v0.x = fmaxf(0.f, v0.x * c0.x + c2.x);
            v0.y = fmaxf(0.f, v0.y * c0.y + c2.y);
            v0.z = fmaxf(0.f, v0.z * c0.z + c2.z);
            v0.w = fmaxf(0.f, v0.w * c0.w + c2.w);
            v1.x = fmaxf(0.f, v1.x * c1.x + c3.x);
            v1.y = fmaxf(0.f, v1.y * c1.y + c3.y);
            v1.z = fmaxf(0.f, v1.z * c1.z + c3.z);
            v1.w = fmaxf(0.f, v1.w * c1.w + c3.w);
          }
          pk.x = f2bf(v0.x) | ((unsigned)f2bf(v0.y) << 16);
          pk.y = f2bf(v0.z) | ((unsigned)f2bf(v0.w) << 16);
          pk.z = f2bf(v1.x) | ((unsigned)f2bf(v1.y) << 16);
          pk.w = f2bf(v1.z) | ((unsigned)f2bf(v1.w) << 16);
        }
        *(uint4*)(sA + m * 64 + ((sc4 ^ ((m >> 1) & 3)) << 4)) = pk;
        *(uint4*)(sB + m * 64 + ((sc4 ^ ((m >> 1) & 3)) << 4)) = pb[h];
      }
    }
    __syncthreads();
    // issue next tile's global loads; they fly during ds_read+MFMA below
    if (k0 + 32 < K) issue(k0 + 32);
    const char* lA = AsB + buf * 8192;
    const char* lB = BsB + buf * 8192;
    bf16x8 a[4], b4[4];
#pragma unroll
    for (int i = 0; i < 4; ++i) {
      int m = wm * 64 + i * 16 + lr;
      a[i] = *(const bf16x8*)(lA + m * 64 + chunkOff);
    }
#pragma unroll
    for (int j = 0; j < 4; ++j) {
      int n = wn * 64 + j * 16 + lr;
      b4[j] = *(const bf16x8*)(lB + n * 64 + chunkOff);
    }
#pragma unroll
    for (int i = 0; i < 4; ++i)
#pragma unroll
      for (int j = 0; j < 4; ++j)
        acc[i][j] = __builtin_amdgcn_mfma_f32_16x16x32_bf16(a[i], b4[j], acc[i][j], 0, 0, 0);
    buf ^= 1;
    // no trailing barrier: next commit writes the other LDS buffer; passing the
    // next barrier implies all waves finished this buffer's MFMA reads.
  }

  // epilogue: C/D layout col=lane&15, row=(lane>>4)*4+reg (m89-verified)
  float csum[4] = {0.f, 0.f, 0.f, 0.f}, cqum[4] = {0.f, 0.f, 0.f, 0.f};
#pragma unroll
  for (int i = 0; i < 4; ++i) {
#pragma unroll
    for (int r = 0; r < 4; ++r) {
      int grow = row0 + wm * 64 + i * 16 + g * 4 + r;
      if (grow >= M) continue;
      const float* zrF = nullptr;
      const unsigned short* zrH = nullptr;
      if (ga.addB) {
        int rid = ga.addIdx ? ga.addIdx[grow] : grow;
        if (ga.addBf16) zrH = (const unsigned short*)ga.addB + (size_t)rid * 256;
        else            zrF = ga.addB + (size_t)rid * 256;
      }
#pragma unroll
      for (int j = 0; j < 4; ++j) {
        int col = col0 + wn * 64 + j * 16 + lr;
        float o = acc[i][j][r];
        if (zrF) o += zrF[col];
        if (zrH) o += bf2f(zrH[col]);
        csum[j] += o; cqum[j] += o * o;
        if (OUT_BF16) ((unsigned short*)Cp)[(size_t)grow * CN + col] = f2bf(o);
        else          ((float*)Cp)[(size_t)grow * CN + col] = o;
      }
    }
  }
  // fused BN stats: per-column sum/sumsq into 16-way shards (cuts same-address contention).
  if (ga.stats) {
    int shard = (blockIdx.x & 15) * 512;
#pragma unroll
    for (int j = 0; j < 4; ++j) {
      float s = csum[j], q = cqum[j];
      s += __shfl_xor(s, 16); q += __shfl_xor(q, 16);
      s += __shfl_xor(s, 32); q += __shfl_xor(q, 32);
      if (g == 0) {
        int col = col0 + wn * 64 + j * 16 + lr;
        atomicAdd(&ga.stats[shard + col], s);
        atomicAdd(&ga.stats[shard + 256 + col], q);
      }
    }
  }
}

// ---------------- batchnorm apply (final outputs only; reads precomputed coef) ----------
template <int SB, int DB>
__global__ void k_bnapply(void* __restrict__ dst, const void* __restrict__ yv,
                          const float* __restrict__ coef, int M, int C) {
  int t = blockIdx.x * 256 + threadIdx.x;
  if (t >= M * C) return;
  int c = t & (C - 1);
  float x = SB ? bf2f(((const unsigned short*)yv)[t]) : ((const float*)yv)[t];
  x = x * coef[c] + coef[C + c];
  x = x > 0.f ? x : 0.f;
  if (DB) ((unsigned short*)dst)[t] = f2bf(x);
  else    ((float*)dst)[t] = x;
}

// ---------------- host ----------------
extern "C" void kernel_launch(void* const* d_in, const int* in_sizes, int n_in,
                              void* d_out, int out_size, void* d_ws, size_t ws_size,
                              hipStream_t stream) {
  constexpr int N = 50000, E = 100000, C5 = 8000, C6 = 12000;
  constexpr int RE = 2 * E, R5 = 5 * C5, R6 = 6 * C6, NC = R5 + R6, CC = C5 + C6;

  const float* node_rep  = (const float*)d_in[0];
  const float* edge_rep  = (const float*)d_in[1];
  const float* cycle_rep = (const float*)d_in[2];
  const int* en  = (const int*)d_in[3];
  const int* cn5 = (const int*)d_in[4];
  const int* cn6 = (const int*)d_in[5];
  const float* nm_w1 = (const float*)d_in[6],  *nm_g1 = (const float*)d_in[7],  *nm_b1 = (const float*)d_in[8];
  const float* nm_w2 = (const float*)d_in[9],  *nm_g2 = (const float*)d_in[10], *nm_b2 = (const float*)d_in[11];
  const float* em_w1 = (const float*)d_in[12], *em_g1 = (const float*)d_in[13], *em_b1 = (const float*)d_in[14];
  const float* em_w2 = (const float*)d_in[15], *em_g2 = (const float*)d_in[16], *em_b2 = (const float*)d_in[17];
  const float* ce_w1 = (const float*)d_in[18], *ce_g1 = (const float*)d_in[19], *ce_b1 = (const float*)d_in[20];
  const float* ce_w2 = (const float*)d_in[21], *ce_g2 = (const float*)d_in[22], *ce_b2 = (const float*)d_in[23];
  const float* cm_w1 = (const float*)d_in[24], *cm_g1 = (const float*)d_in[25], *cm_b1 = (const float*)d_in[26];
  const float* cm_w2 = (const float*)d_in[27], *cm_g2 = (const float*)d_in[28], *cm_b2 = (const float*)d_in[29];
  const float* fm_w  = (const float*)d_in[30], *fm_g  = (const float*)d_in[31], *fm_b  = (const float*)d_in[32];
  float* outD = (float*)d_out;
  float* outN = outD;
  float* outE = outD + (size_t)N * 128;
  float* outC = outD + (size_t)(N + RE) * 128;

  // ---- byte-granular arena ----
  char* wsb = (char*)d_ws;
  size_t off = 0;
  auto A = [&](size_t bytes) { void* p = wsb + off; off += (bytes + 255) & ~(size_t)255; return p; };
  float* deg = (float*)A(N * 4);
  float* d5  = (float*)A(N * 4);
  float* d6  = (float*)A(N * 4);
  float* Ae  = (float*)A((size_t)N * 128 * 4);
  float* Be  = (float*)A((size_t)N * 128 * 4);
  float* Bn  = (float*)A((size_t)N * 128 * 4);
  float* pb2 = (float*)A((size_t)N * 256 * 4);
  float* pb5 = (float*)A((size_t)N * 256 * 4);
  float* pb6 = (float*)A((size_t)N * 256 * 4);
  float* Ac  = (float*)A((size_t)N * 128 * 4);
  size_t zeroBytes = off;                       // everything above is scatter-target
  float* deg2 = (float*)A(N * 4);
  float* dd   = (float*)A(N * 4);
  float* Z    = (float*)A((size_t)N * 256 * 4);
  float* stats = (float*)A(16 * 512 * 4);       // 16-way sharded sums/sumsqs
  float* coefCe1 = (float*)A(512 * 4);
  float* coefCe2 = (float*)A(512 * 4);
  float* coefEm1 = (float*)A(512 * 4);
  float* coefEm2 = (float*)A(512 * 4);
  float* coefNm1 = (float*)A(512 * 4);
  float* coefNm2 = (float*)A(512 * 4);
  float* coefCm1 = (float*)A(512 * 4);
  float* coefCm2 = (float*)A(512 * 4);
  float* coefFm  = (float*)A(512 * 4);
  // bf16 transposed weights
  unsigned short* WtNm1 = (unsigned short*)A((size_t)896 * 256 * 2);
  unsigned short* WtEm1 = (unsigned short*)A((size_t)896 * 256 * 2);
  unsigned short* WtCe1 = (unsigned short*)A((size_t)1408 * 256 * 2);
  unsigned short* WtCm1 = (unsigned short*)A((size_t)640 * 256 * 2);
  unsigned short* WtNm2 = (unsigned short*)A((size_t)256 * 128 * 2);
  unsigned short* WtEm2 = (unsigned short*)A((size_t)256 * 128 * 2);
  unsigned short* WtCe2 = (unsigned short*)A((size_t)256 * 128 * 2);
  unsigned short* WtCm2 = (unsigned short*)A((size_t)256 * 128 * 2);
  unsigned short* WtFm  = (unsigned short*)A((size_t)256 * 128 * 2);
  char*  Yb   = (char*)A((size_t)RE * 256 * 2); // bf16 y arena; aliased as fp32 staging
  unsigned short* O2 = (unsigned short*)A((size_t)RE * 128 * 2);
  if (off > ws_size) return;                    // ~465 MB required

  // bf16 Z table aliases the dead Ac region (Ac consumed by the ce-Z GEMM before cvt).
  unsigned short* Zb = (unsigned short*)Ac;     // [N,256] bf16 = 25.6 MB

  // staging views inside Yb (liveness-disjoint with bf16 y use)
  float* scb = (float*)Yb;              // [CC,640]
  float* Ysc = scb + (size_t)CC * 640;  // [CC,256]

  auto gsum = [&](float* o, int oLd, const float* T, int tLd,
                  const float* scl, const int* idx, int k, int nInst) {
    int tot = nInst * 128;
    k_gsum<<<(tot + 255) / 256, 256, 0, stream>>>(o, oLd, T, tLd, scl, idx, k, nInst);
  };
  auto gsc = [&](float* dst, const float* T1, const float* T2, const int* gidx,
                 const int* sidx, int k, int nInst) {
    int cshift = T2 ? 8 : 7;
    int tot = nInst << cshift;
    k_gsc<<<(tot + 255) / 256, 256, 0, stream>>>(dst, T1, T2, gidx, sidx, k, nInst, cshift);
  };
  auto scat = [&](float* dst, const float* src, const int* idx, int R, int C, int dv) {
    k_scatter<<<R, 128, 0, stream>>>(dst, src, idx, R, C, dv);
  };
  auto wtr = [&](const float* W, unsigned short* Wt, int K, int CN) {
    k_wtrans<<<(K * CN + 255) / 256, 256, 0, stream>>>(W, Wt, K, CN);
  };
  auto gemm = [&](std::initializer_list<Seg> segs, const unsigned short* Wt, int Ktot,
                  int CN, void* Co, int M, bool outBf, const float* addB, const int* addIdx,
                  int addBf, float* st) {
    GemmArgs ga{}; int i = 0;
    for (const Seg& s : segs) ga.segs[i++] = s;
    ga.addB = addB; ga.addIdx = addIdx; ga.stats = st; ga.addBf16 = addBf;
    int K = i * 128;
    dim3 g((M + 127) / 128, CN / 128);
    if (outBf) k_gemm<1><<<g, 256, 0, stream>>>(ga, Wt, Ktot, K, CN, Co, M);
    else       k_gemm<0><<<g, 256, 0, stream>>>(ga, Wt, Ktot, K, CN, Co, M);
  };
  auto zstat = [&]() { hipMemsetAsync(stats, 0, 16 * 512 * sizeof(float), stream); };
  auto fin = [&](float* coef, const float* g, const float* b, int M, int C) {
    k_bnfin<<<1, 256, 0, stream>>>(coef, stats, g, b, M, C);
  };
  auto apply = [&](void* dst, const void* y, const float* coef, int M, int C, int sb, int db) {
    int tot = M * C, gb = (tot + 255) / 256;
    if (sb && db)       k_bnapply<1, 1><<<gb, 256, 0, stream>>>(dst, y, coef, M, C);
    else if (sb && !db) k_bnapply<1, 0><<<gb, 256, 0, stream>>>(dst, y, coef, M, C);
    else if (!sb && db) k_bnapply<0, 1><<<gb, 256, 0, stream>>>(dst, y, coef, M, C);
    else                k_bnapply<0, 0><<<gb, 256, 0, stream>>>(dst, y, coef, M, C);
  };

  // ---- phase 0: degrees + weight transposes ----
  hipMemsetAsync(d_ws, 0, zeroBytes, stream);
  k_count<<<(RE + 255) / 256, 256, 0, stream>>>(deg, en, RE);
  k_count<<<(R5 + 255) / 256, 256, 0, stream>>>(d5, cn5, R5);
  k_count<<<(R6 + 255) / 256, 256, 0, stream>>>(d6, cn6, R6);
  k_scales<<<(N + 255) / 256, 256, 0, stream>>>(deg, d5, d6, deg2, dd, N);
  wtr(nm_w1, WtNm1, 896, 256);  wtr(em_w1, WtEm1, 896, 256);
  wtr(ce_w1, WtCe1, 1408, 256); wtr(cm_w1, WtCm1, 640, 256);
  wtr(nm_w2, WtNm2, 256, 128);  wtr(em_w2, WtEm2, 256, 128);
  wtr(ce_w2, WtCe2, 256, 128);  wtr(cm_w2, WtCm2, 256, 128);
  wtr(fm_w,  WtFm,  256, 128);

  // ---- phase 1: edge-node tables (fused gsum+scatter) ----
  scat(Ae, edge_rep, en, RE, 128, 1);
  gsc(Be, edge_rep, nullptr, nullptr, en, 2, E);
  gsc(Bn, node_rep, nullptr, en, en, 2, E);
  gsc(pb2, Ae, Be, en, en, 2, E);

  // ---- phase 2: cycle tables ----
  gsc(pb5, Ae, Be, cn5, cn5, 5, C5);
  gsc(pb6, Ae, Be, cn6, cn6, 6, C6);
  scat(Ac, cycle_rep, cn5, R5, 128, 1);
  scat(Ac, cycle_rep + (size_t)R5 * 128, cn6, R6, 128, 1);

  // ---- ce stage ----
  gsum(scb + 0,   640, Ae, 128, d5, cn5, 5, C5);
  gsum(scb + 128, 640, Be, 128, d5, cn5, 5, C5);
  gsum(scb + 256, 640, pb5, 256, nullptr, cn5, 5, C5);
  gsum(scb + 384, 640, pb5 + 128, 256, nullptr, cn5, 5, C5);
  gsum(scb + 512, 640, cycle_rep, 128, nullptr, nullptr, 5, C5);
  float* sc6 = scb + (size_t)C5 * 640;
  gsum(sc6 + 0,   640, Ae, 128, d6, cn6, 6, C6);
  gsum(sc6 + 128, 640, Be, 128, d6, cn6, 6, C6);
  gsum(sc6 + 256, 640, pb6, 256, nullptr, cn6, 6, C6);
  gsum(sc6 + 384, 640, pb6 + 128, 256, nullptr, cn6, 6, C6);
  gsum(sc6 + 512, 640, cycle_rep + (size_t)R5 * 128, 128, nullptr, nullptr, 6, C6);
  gemm({{scb, nullptr, nullptr, 640, 768, 0}, {scb + 128, nullptr, nullptr, 640, 896, 0},
        {scb + 256, nullptr, nullptr, 640, 1024, 0}, {scb + 384, nullptr, nullptr, 640, 1152, 0},
        {scb + 512, nullptr, nullptr, 640, 1280, 0}},
       WtCe1, 1408, 256, Ysc, CC, false, nullptr, nullptr, 0, nullptr);
  gemm({{Ae, nullptr, dd, 128, 128, 0}, {Be, nullptr, dd, 128, 256, 0},
        {pb5, nullptr, d5, 256, 384, 0}, {pb5 + 128, nullptr, d5, 256, 512, 0},
        {pb6, nullptr, d6, 256, 384, 0}, {pb6 + 128, nullptr, d6, 256, 512, 0},
        {Ac, nullptr, nullptr, 128, 640, 0}},
       WtCe1, 1408, 256, Z, N, false, nullptr, nullptr, 0, nullptr);
  scat(Z, Ysc, cn5, R5, 256, 5);
  scat(Z, Ysc + (size_t)C5 * 256, cn6, R6, 256, 6);
  k_cvt<<<(N * 256 / 8 + 255) / 256, 256, 0, stream>>>(Zb, Z, N * 256 / 8); // Z -> bf16 (Ac region)
  zstat();
  gemm({{edge_rep, nullptr, nullptr, 128, 0, 0}}, WtCe1, 1408, 256, Yb, RE, true,
       (const float*)Zb, en, 1, stats);
  fin(coefCe1, ce_g1, ce_b1, RE, 256);
  zstat();
  gemm({{Yb, nullptr, nullptr, 256, 0, 1, coefCe1, coefCe1 + 256},
        {Yb + 256, nullptr, nullptr, 256, 128, 1, coefCe1 + 128, coefCe1 + 384}},
       WtCe2, 256, 128, O2, RE, true, nullptr, nullptr, 0, stats);
  fin(coefCe2, ce_g2, ce_b2, RE, 128);

  // ---- em stage ----
  gemm({{Ae, nullptr, deg, 128, 128, 0}, {Be, nullptr, deg, 128, 256, 0},
        {pb2, nullptr, nullptr, 256, 384, 0}, {pb2 + 128, nullptr, nullptr, 256, 512, 0},
        {node_rep, nullptr, deg, 128, 640, 0}, {Bn, nullptr, nullptr, 128, 768, 0}},
       WtEm1, 896, 256, Zb, N, true, nullptr, nullptr, 0, nullptr);
  zstat();
  gemm({{edge_rep, nullptr, nullptr, 128, 0, 0}}, WtEm1, 896, 256, Yb, RE, true,
       (const float*)Zb, en, 1, stats);
  fin(coefEm1, em_g1, em_b1, RE, 256);
  zstat();
  gemm({{Yb, nullptr, nullptr, 256, 0, 1, coefEm1, coefEm1 + 256},
        {Yb + 256, nullptr, nullptr, 256, 128, 1, coefEm1 + 128, coefEm1 + 384}},
       WtEm2, 256, 128, outE, RE, false, nullptr, nullptr, 0, stats); // raw y2 -> outE (scratch)
  fin(coefEm2, em_g2, em_b2, RE, 128);

  // ---- nm stage ----
  zstat();
  gemm({{node_rep, nullptr, nullptr, 128, 0, 0}, {Ae, nullptr, deg2, 128, 128, 0},
        {Be, nullptr, deg2, 128, 256, 0}, {pb2, nullptr, deg, 256, 384, 0},
        {pb2 + 128, nullptr, deg, 256, 512, 0}, {node_rep, nullptr, deg2, 128, 640, 0},
        {Bn, nullptr, deg, 128, 768, 0}},
       WtNm1, 896, 256, Yb, N, true, nullptr, nullptr, 0, stats);
  fin(coefNm1, nm_g1, nm_b1, N, 256);
  zstat();
  gemm({{Yb, nullptr, nullptr, 256, 0, 1, coefNm1, coefNm1 + 256},
        {Yb + 256, nullptr, nullptr, 256, 128, 1, coefNm1 + 128, coefNm1 + 384}},
       WtNm2, 256, 128, outN, N, false, nullptr, nullptr, 0, stats);
  fin(coefNm2, nm_g2, nm_b2, N, 128);
  apply(outN, outN, coefNm2, N, 128, 0, 0);

  // ---- cm stage ----
  gemm({{Ae, nullptr, d5, 128, 0, 0}, {Be, nullptr, d5, 128, 128, 0},
        {pb5, nullptr, nullptr, 256, 256, 0}, {pb5 + 128, nullptr, nullptr, 256, 384, 0}},
       WtCm1, 640, 256, Zb, N, true, nullptr, nullptr, 0, nullptr);
  zstat();
  gemm({{cycle_rep, nullptr, nullptr, 128, 512, 0}}, WtCm1, 640, 256, Yb, R5, true,
       (const float*)Zb, cn5, 1, stats);
  gemm({{Ae, nullptr, d6, 128, 0, 0}, {Be, nullptr, d6, 128, 128, 0},
        {pb6, nullptr, nullptr, 256, 256, 0}, {pb6 + 128, nullptr, nullptr, 256, 384, 0}},
       WtCm1, 640, 256, Zb, N, true, nullptr, nullptr, 0, nullptr);
  gemm({{cycle_rep + (size_t)R5 * 128, nullptr, nullptr, 128, 512, 0}}, WtCm1, 640, 256,
       Yb + (size_t)R5 * 256 * 2, R6, true, (const float*)Zb, cn6, 1, stats);
  fin(coefCm1, cm_g1, cm_b1, NC, 256);
  zstat();
  gemm({{Yb, nullptr, nullptr, 256, 0, 1, coefCm1, coefCm1 + 256},
        {Yb + 256, nullptr, nullptr, 256, 128, 1, coefCm1 + 128, coefCm1 + 384}},
       WtCm2, 256, 128, outC, NC, false, nullptr, nullptr, 0, stats);
  fin(coefCm2, cm_g2, cm_b2, NC, 128);
  apply(outC, outC, coefCm2, NC, 128, 0, 0);

  // ---- fm stage ----
  zstat();
  gemm({{outE, nullptr, nullptr, 128, 0, 0, coefEm2, coefEm2 + 128},
        {O2, nullptr, nullptr, 128, 128, 1, coefCe2, coefCe2 + 128}},
       WtFm, 256, 128, Yb, RE, true, nullptr, nullptr, 0, stats);
  fin(coefFm, fm_g, fm_b, RE, 128);
  apply(outE, Yb, coefFm, RE, 128, 1, 0);
}

// Round 4
// 2795.703 us; speedup vs baseline: 1.4010x; 1.0268x over previous
//
#include <hip/hip_runtime.h>
#include <cstdint>
#include <cstddef>
#include <initializer_list>

typedef short bf16x8 __attribute__((ext_vector_type(8)));
typedef float f32x4 __attribute__((ext_vector_type(4)));

__device__ inline float bf2f(unsigned short h) { return __uint_as_float(((unsigned)h) << 16); }
__device__ inline unsigned short f2bf(float f) {
  unsigned u = __float_as_uint(f);
  u += 0x7fff + ((u >> 16) & 1);
  return (unsigned short)(u >> 16);
}

// ---------------- virtual-A segment for gather-GEMM ----------------
// Each segment is 128 K-rows wide. wk = starting row in W (= col offset in Wt).
// bnsc/bnsh: optional fused BN+ReLU applied to the source on load (per source column).
struct Seg { const void* base; const int* idx; const float* scale; int ld; int wk; int bf16;
             const float* bnsc; const float* bnsh; };
struct GemmArgs { Seg segs[7]; const float* addB; const int* addIdx; float* stats; int addBf16; };

// ---------------- CSR build ----------------
__global__ void k_hist(int* cnt, const int* __restrict__ idx, int R) {
  int r = blockIdx.x * 256 + threadIdx.x;
  if (r < R) atomicAdd(&cnt[idx[r]], 1);
}

// single-block exclusive scan; also zeroes cnt (reused as fill cursor)
__global__ void k_scan(int* __restrict__ cnt, int* __restrict__ off, int n) {
  __shared__ int part[1024];
  int t = threadIdx.x;
  int chunk = (n + 1023) >> 10;
  int b0 = t * chunk, b1 = min(n, b0 + chunk);
  int s = 0;
  for (int i = b0; i < b1; ++i) s += cnt[i];
  part[t] = s;
  __syncthreads();
  for (int d = 1; d < 1024; d <<= 1) {
    int v = (t >= d) ? part[t - d] : 0;
    __syncthreads();
    part[t] += v;
    __syncthreads();
  }
  int run = t ? part[t - 1] : 0;
  for (int i = b0; i < b1; ++i) { off[i] = run; run += cnt[i]; cnt[i] = 0; }
  if (t == 1023) off[n] = part[1023];
}

__global__ void k_fill(int* __restrict__ adj, int* __restrict__ cur,
                       const int* __restrict__ off, const int* __restrict__ idx, int R) {
  int r = blockIdx.x * 256 + threadIdx.x;
  if (r >= R) return;
  int n = idx[r];
  int p = atomicAdd(&cur[n], 1);
  adj[off[n] + p] = r;
}

__global__ void k_scales(const int* __restrict__ ce, const int* __restrict__ c5,
                         const int* __restrict__ c6, float* deg, float* d5, float* d6,
                         float* deg2, float* dd, int n) {
  int i = blockIdx.x * 256 + threadIdx.x;
  if (i < n) {
    float d = (float)ce[i]; deg[i] = d; deg2[i] = d * d;
    float a = (float)c5[i], b = (float)c6[i];
    d5[i] = a; d6[i] = b; dd[i] = a * a + b * b;
  }
}

// ---------------- small kernels ----------------
__global__ void k_wtrans(const float* __restrict__ W, unsigned short* __restrict__ Wt,
                         int K, int CN) {
  int t = blockIdx.x * 256 + threadIdx.x;
  if (t >= K * CN) return;
  int k = t / CN, n = t - k * CN;
  Wt[(size_t)n * K + k] = f2bf(W[t]);
}

__global__ void k_cvt(unsigned short* __restrict__ dst, const float* __restrict__ src, int n8) {
  int i = blockIdx.x * 256 + threadIdx.x;
  if (i >= n8) return;
  const float4* s = (const float4*)(src + (size_t)i * 8);
  float4 a = s[0], b = s[1];
  union { unsigned short u[8]; uint4 v; } o;
  o.u[0] = f2bf(a.x); o.u[1] = f2bf(a.y); o.u[2] = f2bf(a.z); o.u[3] = f2bf(a.w);
  o.u[4] = f2bf(b.x); o.u[5] = f2bf(b.y); o.u[6] = f2bf(b.z); o.u[7] = f2bf(b.w);
  *(uint4*)(dst + (size_t)i * 8) = o.v;
}

// gather-sum over fixed-k groups (ce staging); bf16 or f32 src, bf16 out
template <int SBF>
__global__ void k_gsum(unsigned short* __restrict__ out, int outLd,
                       const void* __restrict__ T, int tLd,
                       const float* __restrict__ scale, const int* __restrict__ idx,
                       int k, int nInst) {
  int t = blockIdx.x * 256 + threadIdx.x;
  int c = t >> 7, ch = t & 127;
  if (c >= nInst) return;
  float acc = 0.f;
  int b0 = c * k;
  for (int j = 0; j < k; ++j) {
    int rid = idx ? idx[b0 + j] : b0 + j;
    float v = SBF ? bf2f(((const unsigned short*)T)[(size_t)rid * tLd + ch])
                  : ((const float*)T)[(size_t)rid * tLd + ch];
    if (scale) v *= scale[rid];
    acc += v;
  }
  out[(size_t)c * outLd + ch] = f2bf(acc);
}

// ---------------- CSR gather kernels (write-once, bf16 out) ----------------
// Ae[n] = sum_{r in adj(n)} edge_rep[r]
__global__ void k_csr_ae(unsigned short* __restrict__ out, const float* __restrict__ src,
                         const int* __restrict__ off, const int* __restrict__ adj, int n) {
  int t = blockIdx.x * 256 + threadIdx.x;
  int node = t >> 7, ch = t & 127;
  if (node >= n) return;
  float a = 0.f;
  int p0 = off[node], p1 = off[node + 1];
  for (int p = p0; p < p1; ++p) a += src[(size_t)adj[p] * 128 + ch];
  out[(size_t)node * 128 + ch] = f2bf(a);
}

// Be[n] = sum_{r in adj(n)} (edge_rep[2e] + edge_rep[2e+1]), e = r/2
__global__ void k_csr_be(unsigned short* __restrict__ out, const float* __restrict__ src,
                         const int* __restrict__ off, const int* __restrict__ adj, int n) {
  int t = blockIdx.x * 256 + threadIdx.x;
  int node = t >> 7, ch = t & 127;
  if (node >= n) return;
  float a = 0.f;
  int p0 = off[node], p1 = off[node + 1];
  for (int p = p0; p < p1; ++p) {
    int e2 = adj[p] & ~1;
    a += src[(size_t)e2 * 128 + ch] + src[(size_t)(e2 + 1) * 128 + ch];
  }
  out[(size_t)node * 128 + ch] = f2bf(a);
}

// Bn[n] = sum_{r in adj(n)} (node_rep[en[2e]] + node_rep[en[2e+1]])
__global__ void k_csr_bn(unsigned short* __restrict__ out, const float* __restrict__ src,
                         const int* __restrict__ en, const int* __restrict__ off,
                         const int* __restrict__ adj, int n) {
  int t = blockIdx.x * 256 + threadIdx.x;
  int node = t >> 7, ch = t & 127;
  if (node >= n) return;
  float a = 0.f;
  int p0 = off[node], p1 = off[node + 1];
  for (int p = p0; p < p1; ++p) {
    int e2 = adj[p] & ~1;
    a += src[(size_t)en[e2] * 128 + ch] + src[(size_t)en[e2 + 1] * 128 + ch];
  }
  out[(size_t)node * 128 + ch] = f2bf(a);
}

// pb2[n][ch] = sum_{r in adj(n)} sum_{j<2} Tab[en[2e+j]][ch&127], Tab = ch<128?Ae:Be (bf16)
__global__ void k_csr_p2(unsigned short* __restrict__ out, const unsigned short* __restrict__ AeB,
                         const unsigned short* __restrict__ BeB, const int* __restrict__ en,
                         const int* __restrict__ off, const int* __restrict__ adj, int n) {
  int t = blockIdx.x * 256 + threadIdx.x;
  int node = t >> 8, ch = t & 255;
  if (node >= n) return;
  const unsigned short* Tab = (ch < 128) ? AeB : BeB;
  int ch7 = ch & 127;
  float a = 0.f;
  int p0 = off[node], p1 = off[node + 1];
  for (int p = p0; p < p1; ++p) {
    int e2 = adj[p] & ~1;
    a += bf2f(Tab[(size_t)en[e2] * 128 + ch7]) + bf2f(Tab[(size_t)en[e2 + 1] * 128 + ch7]);
  }
  out[(size_t)node * 256 + ch] = f2bf(a);
}

// pb5/6[n][ch] = sum_{r in adjX(n)} sum_{j<KK} Tab[cn[KK*(r/KK)+j]][ch&127]
template <int KK>
__global__ void k_csr_p56(unsigned short* __restrict__ out, const unsigned short* __restrict__ AeB,
                          const unsigned short* __restrict__ BeB, const int* __restrict__ cn,
                          const int* __restrict__ off, const int* __restrict__ adj, int n) {
  int t = blockIdx.x * 256 + threadIdx.x;
  int node = t >> 8, ch = t & 255;
  if (node >= n) return;
  const unsigned short* Tab = (ch < 128) ? AeB : BeB;
  int ch7 = ch & 127;
  float a = 0.f;
  int p0 = off[node], p1 = off[node + 1];
  for (int p = p0; p < p1; ++p) {
    int b = (adj[p] / KK) * KK;
#pragma unroll
    for (int j = 0; j < KK; ++j) a += bf2f(Tab[(size_t)cn[b + j] * 128 + ch7]);
  }
  out[(size_t)node * 256 + ch] = f2bf(a);
}

// Ac[n] = sum_{r in adj5(n)} cyc[r] + sum_{r in adj6(n)} cyc[R5+r]
__global__ void k_csr_ac(unsigned short* __restrict__ out, const float* __restrict__ cyc,
                         const int* __restrict__ off5, const int* __restrict__ adj5,
                         const int* __restrict__ off6, const int* __restrict__ adj6,
                         int r5off, int n) {
  int t = blockIdx.x * 256 + threadIdx.x;
  int node = t >> 7, ch = t & 127;
  if (node >= n) return;
  float a = 0.f;
  for (int p = off5[node]; p < off5[node + 1]; ++p) a += cyc[(size_t)adj5[p] * 128 + ch];
  for (int p = off6[node]; p < off6[node + 1]; ++p) a += cyc[(size_t)(r5off + adj6[p]) * 128 + ch];
  out[(size_t)node * 128 + ch] = f2bf(a);
}

// Zb[n] += sum_{r in adj5(n)} Ysc5[r/5] + sum_{r in adj6(n)} Ysc6[r/6]  (in-place bf16)
__global__ void k_zmerge(unsigned short* __restrict__ Zb, const float* __restrict__ Ysc5,
                         const float* __restrict__ Ysc6,
                         const int* __restrict__ off5, const int* __restrict__ adj5,
                         const int* __restrict__ off6, const int* __restrict__ adj6, int n) {
  int t = blockIdx.x * 256 + threadIdx.x;
  int node = t >> 8, ch = t & 255;
  if (node >= n) return;
  float a = bf2f(Zb[(size_t)node * 256 + ch]);
  for (int p = off5[node]; p < off5[node + 1]; ++p) a += Ysc5[(size_t)(adj5[p] / 5) * 256 + ch];
  for (int p = off6[node]; p < off6[node + 1]; ++p) a += Ysc6[(size_t)(adj6[p] / 6) * 256 + ch];
  Zb[(size_t)node * 256 + ch] = f2bf(a);
}

// sharded stats[16][512] -> coef {scale, shift}
__global__ void k_bnfin(float* __restrict__ coef, const float* __restrict__ stats,
                        const float* __restrict__ g, const float* __restrict__ b,
                        int M, int C) {
  int c = threadIdx.x;
  if (c >= C) return;
  float s = 0.f, q = 0.f;
  for (int sh = 0; sh < 16; ++sh) { s += stats[sh * 512 + c]; q += stats[sh * 512 + 256 + c]; }
  float inv = 1.f / (float)M;
  float m = s * inv;
  float v = q * inv - m * m;
  float sc = g[c] * rsqrtf(v + 1e-5f);
  coef[c] = sc;
  coef[C + c] = b[c] - m * sc;
}

// ---------------- MFMA gather-GEMM ----------------
template <int OUT_BF16>
__launch_bounds__(256)
__global__ void k_gemm(GemmArgs ga, const unsigned short* __restrict__ Wt, int Ktot,
                       int K, int CN, void* __restrict__ Cp, int M) {
  __shared__ char AsB[2 * 128 * 64];
  __shared__ char BsB[2 * 128 * 64];
  int tid = threadIdx.x;
  int row0 = blockIdx.x * 128, col0 = blockIdx.y * 128;
  int l = tid & 63, w = tid >> 6;
  int wm = w >> 1, wn = w & 1;
  int lr = l & 15, g = l >> 4;
  int chunkOff = (g ^ ((lr >> 1) & 3)) << 4;
  int sm = tid >> 2;
  int sc4 = tid & 3;
  f32x4 acc[4][4] = {};

  uint4 pa0[2], pa1[2], pb[2];
  float psc[2];
  float4 c0, c1, c2, c3;

  auto issue = [&](int k0n) {
    Seg sg = ga.segs[k0n >> 7];
    int kin = k0n & 127;
#pragma unroll
    for (int h = 0; h < 2; ++h) {
      int m = sm + 64 * h;
      int grow = row0 + m;
      uint4 z4 = make_uint4(0, 0, 0, 0);
      pa0[h] = z4; pa1[h] = z4; psc[h] = 1.f;
      if (grow < M) {
        int rid = sg.idx ? sg.idx[grow] : grow;
        if (sg.bf16) {
          pa0[h] = *(const uint4*)((const unsigned short*)sg.base + (size_t)rid * sg.ld + kin + sc4 * 8);
          if (sg.scale) psc[h] = sg.scale[rid];
        } else {
          const float* fp = (const float*)sg.base + (size_t)rid * sg.ld + kin + sc4 * 8;
          pa0[h] = *(const uint4*)fp;
          pa1[h] = *(const uint4*)(fp + 4);
          if (sg.scale) psc[h] = sg.scale[rid];
        }
      }
      pb[h] = *(const uint4*)(Wt + (size_t)(col0 + m) * Ktot + sg.wk + kin + sc4 * 8);
    }
    if (sg.bnsc) {
      const float* sp = sg.bnsc + kin + sc4 * 8;
      const float* hp = sg.bnsh + kin + sc4 * 8;
      c0 = *(const float4*)sp; c1 = *(const float4*)(sp + 4);
      c2 = *(const float4*)hp; c3 = *(const float4*)(hp + 4);
    }
  };

  issue(0);
  int buf = 0;
  for (int k0 = 0; k0 < K; k0 += 32) {
    {
      Seg sg = ga.segs[k0 >> 7];
      char* sA = AsB + buf * 8192;
      char* sB = BsB + buf * 8192;
#pragma unroll
      for (int h = 0; h < 2; ++h) {
        int m = sm + 64 * h;
        uint4 pk;
        if (sg.bf16) {
          pk = pa0[h];
          if (sg.bnsc) {
            unsigned short* u = (unsigned short*)&pk;
            float cs0[8] = {c0.x, c0.y, c0.z, c0.w, c1.x, c1.y, c1.z, c1.w};
            float sh0[8] = {c2.x, c2.y, c2.z, c2.w, c3.x, c3.y, c3.z, c3.w};
#pragma unroll
            for (int e = 0; e < 8; ++e) {
              float f = fmaxf(0.f, bf2f(u[e]) * cs0[e] + sh0[e]);
              u[e] = f2bf(f);
            }
          } else if (sg.scale) {
            unsigned short* u = (unsigned short*)&pk;
            float s = psc[h];
#pragma unroll
            for (int e = 0; e < 8; ++e) u[e] = f2bf(bf2f(u[e]) * s);
          }
        } else {
          float4 v0 = *(const float4*)&pa0[h];
          float4 v1 = *(const float4*)&pa1[h];
          float s = psc[h];
          v0.x *= s; v0.y *= s; v0.z *= s; v0.w *= s;
          v1.x *= s; v1.y *= s; v1.z *= s; v1.w *= s;
          if (sg.bnsc) {
            v0.x = fmaxf(0.f, v0.x * c0.x + c2.x);
            v0.y = fmaxf(0.f, v0.y * c0.y + c2.y);
            v0.z = fmaxf(0.f, v0.z * c0.z + c2.z);
            v0.w = fmaxf(0.f, v0.w * c0.w + c2.w);
            v1.x = fmaxf(0.f, v1.x * c1.x + c3.x);
            v1.y = fmaxf(0.f, v1.y * c1.y + c3.y);
            v1.z = fmaxf(0.f, v1.z * c1.z + c3.z);
            v1.w = fmaxf(0.f, v1.w * c1.w + c3.w);
          }
          pk.x = f2bf(v0.x) | ((unsigned)f2bf(v0.y) << 16);
          pk.y = f2bf(v0.z) | ((unsigned)f2bf(v0.w) << 16);
          pk.z = f2bf(v1.x) | ((unsigned)f2bf(v1.y) << 16);
          pk.w = f2bf(v1.z) | ((unsigned)f2bf(v1.w) << 16);
        }
        *(uint4*)(sA + m * 64 + ((sc4 ^ ((m >> 1) & 3)) << 4)) = pk;
        *(uint4*)(sB + m * 64 + ((sc4 ^ ((m >> 1) & 3)) << 4)) = pb[h];
      }
    }
    __syncthreads();
    if (k0 + 32 < K) issue(k0 + 32);
    const char* lA = AsB + buf * 8192;
    const char* lB = BsB + buf * 8192;
    bf16x8 a[4], b4[4];
#pragma unroll
    for (int i = 0; i < 4; ++i) {
      int m = wm * 64 + i * 16 + lr;
      a[i] = *(const bf16x8*)(lA + m * 64 + chunkOff);
    }
#pragma unroll
    for (int j = 0; j < 4; ++j) {
      int n = wn * 64 + j * 16 + lr;
      b4[j] = *(const bf16x8*)(lB + n * 64 + chunkOff);
    }
#pragma unroll
    for (int i = 0; i < 4; ++i)
#pragma unroll
      for (int j = 0; j < 4; ++j)
        acc[i][j] = __builtin_amdgcn_mfma_f32_16x16x32_bf16(a[i], b4[j], acc[i][j], 0, 0, 0);
    buf ^= 1;
  }

  float csum[4] = {0.f, 0.f, 0.f, 0.f}, cqum[4] = {0.f, 0.f, 0.f, 0.f};
#pragma unroll
  for (int i = 0; i < 4; ++i) {
#pragma unroll
    for (int r = 0; r < 4; ++r) {
      int grow = row0 + wm * 64 + i * 16 + g * 4 + r;
      if (grow >= M) continue;
      const float* zrF = nullptr;
      const unsigned short* zrH = nullptr;
      if (ga.addB) {
        int rid = ga.addIdx ? ga.addIdx[grow] : grow;
        if (ga.addBf16) zrH = (const unsigned short*)ga.addB + (size_t)rid * 256;
        else            zrF = ga.addB + (size_t)rid * 256;
      }
#pragma unroll
      for (int j = 0; j < 4; ++j) {
        int col = col0 + wn * 64 + j * 16 + lr;
        float o = acc[i][j][r];
        if (zrF) o += zrF[col];
        if (zrH) o += bf2f(zrH[col]);
        csum[j] += o; cqum[j] += o * o;
        if (OUT_BF16) ((unsigned short*)Cp)[(size_t)grow * CN + col] = f2bf(o);
        else          ((float*)Cp)[(size_t)grow * CN + col] = o;
      }
    }
  }
  if (ga.stats) {
    int shard = (blockIdx.x & 15) * 512;
#pragma unroll
    for (int j = 0; j < 4; ++j) {
      float s = csum[j], q = cqum[j];
      s += __shfl_xor(s, 16); q += __shfl_xor(q, 16);
      s += __shfl_xor(s, 32); q += __shfl_xor(q, 32);
      if (g == 0) {
        int col = col0 + wn * 64 + j * 16 + lr;
        atomicAdd(&ga.stats[shard + col], s);
        atomicAdd(&ga.stats[shard + 256 + col], q);
      }
    }
  }
}

// ---------------- batchnorm apply ----------------
template <int SB, int DB>
__global__ void k_bnapply(void* __restrict__ dst, const void* __restrict__ yv,
                          const float* __restrict__ coef, int M, int C) {
  int t = blockIdx.x * 256 + threadIdx.x;
  if (t >= M * C) return;
  int c = t & (C - 1);
  float x = SB ? bf2f(((const unsigned short*)yv)[t]) : ((const float*)yv)[t];
  x = x * coef[c] + coef[C + c];
  x = x > 0.f ? x : 0.f;
  if (DB) ((unsigned short*)dst)[t] = f2bf(x);
  else    ((float*)dst)[t] = x;
}

// ---------------- host ----------------
extern "C" void kernel_launch(void* const* d_in, const int* in_sizes, int n_in,
                              void* d_out, int out_size, void* d_ws, size_t ws_size,
                              hipStream_t stream) {
  constexpr int N = 50000, E = 100000, C5 = 8000, C6 = 12000;
  constexpr int RE = 2 * E, R5 = 5 * C5, R6 = 6 * C6, NC = R5 + R6, CC = C5 + C6;

  const float* node_rep  = (const float*)d_in[0];
  const float* edge_rep  = (const float*)d_in[1];
  const float* cycle_rep = (const float*)d_in[2];
  const int* en  = (const int*)d_in[3];
  const int* cn5 = (const int*)d_in[4];
  const int* cn6 = (const int*)d_in[5];
  const float* nm_w1 = (const float*)d_in[6],  *nm_g1 = (const float*)d_in[7],  *nm_b1 = (const float*)d_in[8];
  const float* nm_w2 = (const float*)d_in[9],  *nm_g2 = (const float*)d_in[10], *nm_b2 = (const float*)d_in[11];
  const float* em_w1 = (const float*)d_in[12], *em_g1 = (const float*)d_in[13], *em_b1 = (const float*)d_in[14];
  const float* em_w2 = (const float*)d_in[15], *em_g2 = (const float*)d_in[16], *em_b2 = (const float*)d_in[17];
  const float* ce_w1 = (const float*)d_in[18], *ce_g1 = (const float*)d_in[19], *ce_b1 = (const float*)d_in[20];
  const float* ce_w2 = (const float*)d_in[21], *ce_g2 = (const float*)d_in[22], *ce_b2 = (const float*)d_in[23];
  const float* cm_w1 = (const float*)d_in[24], *cm_g1 = (const float*)d_in[25], *cm_b1 = (const float*)d_in[26];
  const float* cm_w2 = (const float*)d_in[27], *cm_g2 = (const float*)d_in[28], *cm_b2 = (const float*)d_in[29];
  const float* fm_w  = (const float*)d_in[30], *fm_g  = (const float*)d_in[31], *fm_b  = (const float*)d_in[32];
  float* outD = (float*)d_out;
  float* outN = outD;
  float* outE = outD + (size_t)N * 128;
  float* outC = outD + (size_t)(N + RE) * 128;

  // ---- arena ----
  char* wsb = (char*)d_ws;
  size_t off = 0;
  auto A = [&](size_t bytes) { void* p = wsb + off; off += (bytes + 255) & ~(size_t)255; return p; };
  float* deg  = (float*)A(N * 4);
  float* d5   = (float*)A(N * 4);
  float* d6   = (float*)A(N * 4);
  float* deg2 = (float*)A(N * 4);
  float* dd   = (float*)A(N * 4);
  int* cntE = (int*)A(N * 4);          // contiguous cnt block for one memset
  int* cnt5 = (int*)A(N * 4);
  int* cnt6 = (int*)A(N * 4);
  size_t cntBytes = (char*)A(0) - (char*)cntE;
  int* offE = (int*)A((N + 1) * 4);
  int* off5 = (int*)A((N + 1) * 4);
  int* off6 = (int*)A((N + 1) * 4);
  int* adjE = (int*)A((size_t)RE * 4);
  int* adj5 = (int*)A((size_t)R5 * 4);
  int* adj6 = (int*)A((size_t)R6 * 4);
  float* stats = (float*)A(16 * 512 * 4);
  float* coefCe1 = (float*)A(512 * 4);
  float* coefCe2 = (float*)A(512 * 4);
  float* coefEm1 = (float*)A(512 * 4);
  float* coefEm2 = (float*)A(512 * 4);
  float* coefNm1 = (float*)A(512 * 4);
  float* coefNm2 = (float*)A(512 * 4);
  float* coefCm1 = (float*)A(512 * 4);
  float* coefCm2 = (float*)A(512 * 4);
  float* coefFm  = (float*)A(512 * 4);
  unsigned short* WtNm1 = (unsigned short*)A((size_t)896 * 256 * 2);
  unsigned short* WtEm1 = (unsigned short*)A((size_t)896 * 256 * 2);
  unsigned short* WtCe1 = (unsigned short*)A((size_t)1408 * 256 * 2);
  unsigned short* WtCm1 = (unsigned short*)A((size_t)640 * 256 * 2);
  unsigned short* WtNm2 = (unsigned short*)A((size_t)256 * 128 * 2);
  unsigned short* WtEm2 = (unsigned short*)A((size_t)256 * 128 * 2);
  unsigned short* WtCe2 = (unsigned short*)A((size_t)256 * 128 * 2);
  unsigned short* WtCm2 = (unsigned short*)A((size_t)256 * 128 * 2);
  unsigned short* WtFm  = (unsigned short*)A((size_t)256 * 128 * 2);
  // bf16 tables
  unsigned short* AeB  = (unsigned short*)A((size_t)N * 128 * 2);
  unsigned short* BeB  = (unsigned short*)A((size_t)N * 128 * 2);
  unsigned short* BnB  = (unsigned short*)A((size_t)N * 128 * 2);
  unsigned short* AcB  = (unsigned short*)A((size_t)N * 128 * 2);
  unsigned short* pb2B = (unsigned short*)A((size_t)N * 256 * 2);
  unsigned short* pb5B = (unsigned short*)A((size_t)N * 256 * 2);
  unsigned short* pb6B = (unsigned short*)A((size_t)N * 256 * 2);
  unsigned short* Zb   = (unsigned short*)A((size_t)N * 256 * 2);
  unsigned short* edgeB = (unsigned short*)A((size_t)RE * 128 * 2);
  unsigned short* nodeB = (unsigned short*)A((size_t)N * 128 * 2);
  unsigned short* cycB  = (unsigned short*)A((size_t)NC * 128 * 2);
  unsigned short* Eb    = (unsigned short*)A((size_t)RE * 128 * 2);
  char*  Yb   = (char*)A((size_t)RE * 256 * 2); // bf16 y arena; aliased as staging
  unsigned short* O2 = (unsigned short*)A((size_t)RE * 128 * 2);
  if (off > ws_size) return;

  // staging views inside Yb
  unsigned short* scbB = (unsigned short*)Yb;              // [CC,640] bf16
  float* Ysc = (float*)(Yb + (size_t)CC * 640 * 2);        // [CC,256] f32

  auto gsumB = [&](unsigned short* o, int oLd, const unsigned short* T, int tLd,
                   const float* scl, const int* idx, int k, int nInst) {
    int tot = nInst * 128;
    k_gsum<1><<<(tot + 255) / 256, 256, 0, stream>>>(o, oLd, T, tLd, scl, idx, k, nInst);
  };
  auto wtr = [&](const float* W, unsigned short* Wt, int K, int CN) {
    k_wtrans<<<(K * CN + 255) / 256, 256, 0, stream>>>(W, Wt, K, CN);
  };
  auto cvt = [&](unsigned short* dst, const float* src, size_t elems) {
    int n8 = (int)(elems / 8);
    k_cvt<<<(n8 + 255) / 256, 256, 0, stream>>>(dst, src, n8);
  };
  auto gemm = [&](std::initializer_list<Seg> segs, const unsigned short* Wt, int Ktot,
                  int CN, void* Co, int M, bool outBf, const float* addB, const int* addIdx,
                  int addBf, float* st) {
    GemmArgs ga{}; int i = 0;
    for (const Seg& s : segs) ga.segs[i++] = s;
    ga.addB = addB; ga.addIdx = addIdx; ga.stats = st; ga.addBf16 = addBf;
    int K = i * 128;
    dim3 g((M + 127) / 128, CN / 128);
    if (outBf) k_gemm<1><<<g, 256, 0, stream>>>(ga, Wt, Ktot, K, CN, Co, M);
    else       k_gemm<0><<<g, 256, 0, stream>>>(ga, Wt, Ktot, K, CN, Co, M);
  };
  auto zstat = [&]() { hipMemsetAsync(stats, 0, 16 * 512 * sizeof(float), stream); };
  auto fin = [&](float* coef, const float* g, const float* b, int M, int C) {
    k_bnfin<<<1, 256, 0, stream>>>(coef, stats, g, b, M, C);
  };
  auto apply = [&](void* dst, const void* y, const float* coef, int M, int C, int sb, int db) {
    int tot = M * C, gb = (tot + 255) / 256;
    if (sb && db)       k_bnapply<1, 1><<<gb, 256, 0, stream>>>(dst, y, coef, M, C);
    else if (sb && !db) k_bnapply<1, 0><<<gb, 256, 0, stream>>>(dst, y, coef, M, C);
    else if (!sb && db) k_bnapply<0, 1><<<gb, 256, 0, stream>>>(dst, y, coef, M, C);
    else                k_bnapply<0, 0><<<gb, 256, 0, stream>>>(dst, y, coef, M, C);
  };

  // ---- phase 0: CSR build + scales + weight/input casts ----
  hipMemsetAsync(cntE, 0, cntBytes, stream);
  k_hist<<<(RE + 255) / 256, 256, 0, stream>>>(cntE, en, RE);
  k_hist<<<(R5 + 255) / 256, 256, 0, stream>>>(cnt5, cn5, R5);
  k_hist<<<(R6 + 255) / 256, 256, 0, stream>>>(cnt6, cn6, R6);
  k_scales<<<(N + 255) / 256, 256, 0, stream>>>(cntE, cnt5, cnt6, deg, d5, d6, deg2, dd, N);
  k_scan<<<1, 1024, 0, stream>>>(cntE, offE, N);
  k_scan<<<1, 1024, 0, stream>>>(cnt5, off5, N);
  k_scan<<<1, 1024, 0, stream>>>(cnt6, off6, N);
  k_fill<<<(RE + 255) / 256, 256, 0, stream>>>(adjE, cntE, offE, en, RE);
  k_fill<<<(R5 + 255) / 256, 256, 0, stream>>>(adj5, cnt5, off5, cn5, R5);
  k_fill<<<(R6 + 255) / 256, 256, 0, stream>>>(adj6, cnt6, off6, cn6, R6);
  wtr(nm_w1, WtNm1, 896, 256);  wtr(em_w1, WtEm1, 896, 256);
  wtr(ce_w1, WtCe1, 1408, 256); wtr(cm_w1, WtCm1, 640, 256);
  wtr(nm_w2, WtNm2, 256, 128);  wtr(em_w2, WtEm2, 256, 128);
  wtr(ce_w2, WtCe2, 256, 128);  wtr(cm_w2, WtCm2, 256, 128);
  wtr(fm_w,  WtFm,  256, 128);
  cvt(edgeB, edge_rep, (size_t)RE * 128);
  cvt(nodeB, node_rep, (size_t)N * 128);
  cvt(cycB,  cycle_rep, (size_t)NC * 128);

  // ---- phase 1/2: tables via CSR gather (write-once bf16, no atomics) ----
  {
    int g128 = (N * 128 + 255) / 256, g256 = (N * 256 + 255) / 256;
    k_csr_ae<<<g128, 256, 0, stream>>>(AeB, edge_rep, offE, adjE, N);
    k_csr_be<<<g128, 256, 0, stream>>>(BeB, edge_rep, offE, adjE, N);
    k_csr_bn<<<g128, 256, 0, stream>>>(BnB, node_rep, en, offE, adjE, N);
    k_csr_ac<<<g128, 256, 0, stream>>>(AcB, cycle_rep, off5, adj5, off6, adj6, R5, N);
    k_csr_p2<<<g256, 256, 0, stream>>>(pb2B, AeB, BeB, en, offE, adjE, N);
    k_csr_p56<5><<<g256, 256, 0, stream>>>(pb5B, AeB, BeB, cn5, off5, adj5, N);
    k_csr_p56<6><<<g256, 256, 0, stream>>>(pb6B, AeB, BeB, cn6, off6, adj6, N);
  }

  // ---- ce stage ----
  gsumB(scbB + 0,   640, AeB, 128, d5, cn5, 5, C5);
  gsumB(scbB + 128, 640, BeB, 128, d5, cn5, 5, C5);
  gsumB(scbB + 256, 640, pb5B, 256, nullptr, cn5, 5, C5);
  gsumB(scbB + 384, 640, pb5B + 128, 256, nullptr, cn5, 5, C5);
  gsumB(scbB + 512, 640, cycB, 128, nullptr, nullptr, 5, C5);
  unsigned short* sc6B = scbB + (size_t)C5 * 640;
  gsumB(sc6B + 0,   640, AeB, 128, d6, cn6, 6, C6);
  gsumB(sc6B + 128, 640, BeB, 128, d6, cn6, 6, C6);
  gsumB(sc6B + 256, 640, pb6B, 256, nullptr, cn6, 6, C6);
  gsumB(sc6B + 384, 640, pb6B + 128, 256, nullptr, cn6, 6, C6);
  gsumB(sc6B + 512, 640, cycB + (size_t)R5 * 128, 128, nullptr, nullptr, 6, C6);
  gemm({{scbB, nullptr, nullptr, 640, 768, 1}, {scbB + 128, nullptr, nullptr, 640, 896, 1},
        {scbB + 256, nullptr, nullptr, 640, 1024, 1}, {scbB + 384, nullptr, nullptr, 640, 1152, 1},
        {scbB + 512, nullptr, nullptr, 640, 1280, 1}},
       WtCe1, 1408, 256, Ysc, CC, false, nullptr, nullptr, 0, nullptr);
  gemm({{AeB, nullptr, dd, 128, 128, 1}, {BeB, nullptr, dd, 128, 256, 1},
        {pb5B, nullptr, d5, 256, 384, 1}, {pb5B + 128, nullptr, d5, 256, 512, 1},
        {pb6B, nullptr, d6, 256, 384, 1}, {pb6B + 128, nullptr, d6, 256, 512, 1},
        {AcB, nullptr, nullptr, 128, 640, 1}},
       WtCe1, 1408, 256, Zb, N, true, nullptr, nullptr, 0, nullptr);
  k_zmerge<<<(N * 256 + 255) / 256, 256, 0, stream>>>(
      Zb, Ysc, Ysc + (size_t)C5 * 256, off5, adj5, off6, adj6, N);
  zstat();
  gemm({{edgeB, nullptr, nullptr, 128, 0, 1}}, WtCe1, 1408, 256, Yb, RE, true,
       (const float*)Zb, en, 1, stats);
  fin(coefCe1, ce_g1, ce_b1, RE, 256);
  zstat();
  gemm({{Yb, nullptr, nullptr, 256, 0, 1, coefCe1, coefCe1 + 256},
        {Yb + 256, nullptr, nullptr, 256, 128, 1, coefCe1 + 128, coefCe1 + 384}},
       WtCe2, 256, 128, O2, RE, true, nullptr, nullptr, 0, stats);
  fin(coefCe2, ce_g2, ce_b2, RE, 128);

  // ---- em stage ----
  gemm({{AeB, nullptr, deg, 128, 128, 1}, {BeB, nullptr, deg, 128, 256, 1},
        {pb2B, nullptr, nullptr, 256, 384, 1}, {pb2B + 128, nullptr, nullptr, 256, 512, 1},
        {nodeB, nullptr, deg, 128, 640, 1}, {BnB, nullptr, nullptr, 128, 768, 1}},
       WtEm1, 896, 256, Zb, N, true, nullptr, nullptr, 0, nullptr);
  zstat();
  gemm({{edgeB, nullptr, nullptr, 128, 0, 1}}, WtEm1, 896, 256, Yb, RE, true,
       (const float*)Zb, en, 1, stats);
  fin(coefEm1, em_g1, em_b1, RE, 256);
  zstat();
  gemm({{Yb, nullptr, nullptr, 256, 0, 1, coefEm1, coefEm1 + 256},
        {Yb + 256, nullptr, nullptr, 256, 128, 1, coefEm1 + 128, coefEm1 + 384}},
       WtEm2, 256, 128, Eb, RE, true, nullptr, nullptr, 0, stats); // raw y2 -> Eb bf16
  fin(coefEm2, em_g2, em_b2, RE, 128);

  // ---- nm stage ----
  zstat();
  gemm({{nodeB, nullptr, nullptr, 128, 0, 1}, {AeB, nullptr, deg2, 128, 128, 1},
        {BeB, nullptr, deg2, 128, 256, 1}, {pb2B, nullptr, deg, 256, 384, 1},
        {pb2B + 128, nullptr, deg, 256, 512, 1}, {nodeB, nullptr, deg2, 128, 640, 1},
        {BnB, nullptr, deg, 128, 768, 1}},
       WtNm1, 896, 256, Yb, N, true, nullptr, nullptr, 0, stats);
  fin(coefNm1, nm_g1, nm_b1, N, 256);
  zstat();
  gemm({{Yb, nullptr, nullptr, 256, 0, 1, coefNm1, coefNm1 + 256},
        {Yb + 256, nullptr, nullptr, 256, 128, 1, coefNm1 + 128, coefNm1 + 384}},
       WtNm2, 256, 128, outN, N, false, nullptr, nullptr, 0, stats);
  fin(coefNm2, nm_g2, nm_b2, N, 128);
  apply(outN, outN, coefNm2, N, 128, 0, 0);

  // ---- cm stage ----
  gemm({{AeB, nullptr, d5, 128, 0, 1}, {BeB, nullptr, d5, 128, 128, 1},
        {pb5B, nullptr, nullptr, 256, 256, 1}, {pb5B + 128, nullptr, nullptr, 256, 384, 1}},
       WtCm1, 640, 256, Zb, N, true, nullptr, nullptr, 0, nullptr);
  zstat();
  gemm({{cycB, nullptr, nullptr, 128, 512, 1}}, WtCm1, 640, 256, Yb, R5, true,
       (const float*)Zb, cn5, 1, stats);
  gemm({{AeB, nullptr, d6, 128, 0, 1}, {BeB, nullptr, d6, 128, 128, 1},
        {pb6B, nullptr, nullptr, 256, 256, 1}, {pb6B + 128, nullptr, nullptr, 256, 384, 1}},
       WtCm1, 640, 256, Zb, N, true, nullptr, nullptr, 0, nullptr);
  gemm({{cycB + (size_t)R5 * 128, nullptr, nullptr, 128, 512, 1}}, WtCm1, 640, 256,
       Yb + (size_t)R5 * 256 * 2, R6, true, (const float*)Zb, cn6, 1, stats);
  fin(coefCm1, cm_g1, cm_b1, NC, 256);
  zstat();
  gemm({{Yb, nullptr, nullptr, 256, 0, 1, coefCm1, coefCm1 + 256},
        {Yb + 256, nullptr, nullptr, 256, 128, 1, coefCm1 + 128, coefCm1 + 384}},
       WtCm2, 256, 128, outC, NC, false, nullptr, nullptr, 0, stats);
  fin(coefCm2, cm_g2, cm_b2, NC, 128);
  apply(outC, outC, coefCm2, NC, 128, 0, 0);

  // ---- fm stage ----
  zstat();
  gemm({{Eb, nullptr, nullptr, 128, 0, 1, coefEm2, coefEm2 + 128},
        {O2, nullptr, nullptr, 128, 128, 1, coefCe2, coefCe2 + 128}},
       WtFm, 256, 128, Yb, RE, true, nullptr, nullptr, 0, stats);
  fin(coefFm, fm_g, fm_b, RE, 128);
  apply(outE, Yb, coefFm, RE, 128, 1, 0);
}